// Round 1
// baseline (1218.922 us; speedup 1.0000x reference)
//
#include <hip/hip_runtime.h>
#include <cstdint>
#include <cstddef>

#define NFEAT 128
#define TGRAPH 10
#define NGRAPHS 512
#define BN_EPS 1e-5f

// ---------------- CSR build ----------------
__global__ void k_degree(const int* __restrict__ dst, int* __restrict__ deg, int E) {
    int e = blockIdx.x * blockDim.x + threadIdx.x;
    if (e < E) atomicAdd(&deg[dst[e]], 1);
}

// chunk = 1024 elements per block (256 threads x 4)
__global__ void k_scan_partial(const int* __restrict__ deg, int* __restrict__ out,
                               int* __restrict__ bsums, int N) {
    __shared__ int s[256];
    int t = threadIdx.x;
    int base = blockIdx.x * 1024 + t * 4;
    int v0 = 0, v1 = 0, v2 = 0, v3 = 0;
    if (base + 0 < N) v0 = deg[base + 0];
    if (base + 1 < N) v1 = deg[base + 1];
    if (base + 2 < N) v2 = deg[base + 2];
    if (base + 3 < N) v3 = deg[base + 3];
    int sum = v0 + v1 + v2 + v3;
    s[t] = sum;
    __syncthreads();
    for (int off = 1; off < 256; off <<= 1) {
        int x = 0;
        if (t >= off) x = s[t - off];
        __syncthreads();
        if (t >= off) s[t] += x;
        __syncthreads();
    }
    int run = s[t] - sum;  // exclusive prefix of this thread within block
    if (base + 0 < N) out[base + 0] = run; run += v0;
    if (base + 1 < N) out[base + 1] = run; run += v1;
    if (base + 2 < N) out[base + 2] = run; run += v2;
    if (base + 3 < N) out[base + 3] = run;
    if (t == 255) bsums[blockIdx.x] = s[255];
}

__global__ void k_scan_bsums(int* bsums, int B) {
    __shared__ int s[256];
    int t = threadIdx.x;
    int v = (t < B) ? bsums[t] : 0;
    s[t] = v;
    __syncthreads();
    for (int off = 1; off < 256; off <<= 1) {
        int x = 0;
        if (t >= off) x = s[t - off];
        __syncthreads();
        if (t >= off) s[t] += x;
        __syncthreads();
    }
    if (t < B) bsums[t] = s[t] - v;  // exclusive
}

__global__ void k_add_offsets(int* __restrict__ rowptr, const int* __restrict__ bsums,
                              int N, int E) {
    int i = blockIdx.x * blockDim.x + threadIdx.x;
    if (i < N) rowptr[i] += bsums[i >> 10];
    if (i == 0) rowptr[N] = E;
}

__global__ void k_fill(const int* __restrict__ src, const int* __restrict__ dst,
                       int* __restrict__ cursor, int* __restrict__ adj, int E) {
    int e = blockIdx.x * blockDim.x + threadIdx.x;
    if (e < E) {
        int p = atomicAdd(&cursor[dst[e]], 1);
        adj[p] = src[e];
    }
}

// ---------------- aggregation: xa[n] = x[n] + sum_{s in nbr(n)} x[s] ----------------
// one wave (64 lanes) per node; lane holds cols 2*lane, 2*lane+1
__global__ __launch_bounds__(256) void k_aggregate(const float* __restrict__ X,
                                                   const int* __restrict__ rowptr,
                                                   const int* __restrict__ adj,
                                                   float* __restrict__ XA, int N) {
    int wid = (blockIdx.x * blockDim.x + threadIdx.x) >> 6;
    int lane = threadIdx.x & 63;
    if (wid >= N) return;
    const float2* xr = (const float2*)(X + (size_t)wid * NFEAT);
    float2 acc = xr[lane];  // GIN eps=0: (x + agg)
    int r0 = rowptr[wid], r1 = rowptr[wid + 1];
    for (int e = r0; e < r1; ++e) {
        int s = adj[e];
        float2 v = ((const float2*)(X + (size_t)s * NFEAT))[lane];
        acc.x += v.x;
        acc.y += v.y;
    }
    ((float2*)(XA + (size_t)wid * NFEAT))[lane] = acc;
}

// ---------------- GEMM: C[N,128] = op(A) @ W[128,128] + bias ----------------
// op(A) = BN_RELU_IN ? relu(A*scale[k]+shift[k]) : A ; output relu optional.
// 64 rows per block, 256 threads, thread computes 8 rows x 4 cols.
template <bool BN_RELU_IN, bool RELU_OUT>
__global__ __launch_bounds__(256) void k_gemm128(const float* __restrict__ A,
                                                 const float* __restrict__ W,
                                                 const float* __restrict__ bias,
                                                 const float* __restrict__ scale,
                                                 const float* __restrict__ shift,
                                                 float* __restrict__ C, int N) {
    __shared__ float s_w[32][NFEAT];   // 16 KB: W k-chunk
    __shared__ float s_a[64][36];      // 9 KB: A chunk, row-major, pad 4

    int tid = threadIdx.x;
    int tx = tid & 31;   // cols tx*4 .. tx*4+3
    int ty = tid >> 5;   // rows ty*8 .. ty*8+7
    int row0 = blockIdx.x * 64;

    float acc[8][4];
#pragma unroll
    for (int i = 0; i < 8; i++)
#pragma unroll
        for (int j = 0; j < 4; j++) acc[i][j] = 0.f;

    int arow = tid >> 2;        // 0..63
    int af = (tid & 3) * 8;     // 0,8,16,24
    int gr = row0 + arow;

    for (int kc = 0; kc < 4; ++kc) {
        __syncthreads();
        // stage W chunk [32][128]
        {
            int k = tid >> 3;
            int j0 = (tid & 7) * 16;
            const float4* wsrc = (const float4*)(W + (size_t)(kc * 32 + k) * NFEAT + j0);
            float4* wdst = (float4*)(&s_w[k][j0]);
            wdst[0] = wsrc[0];
            wdst[1] = wsrc[1];
            wdst[2] = wsrc[2];
            wdst[3] = wsrc[3];
        }
        // stage A chunk [64 rows][32 k], 8 k's per thread
        {
            float va[8];
            if (gr < N) {
                const float* ap = A + (size_t)gr * NFEAT + kc * 32 + af;
                float4 p0 = ((const float4*)ap)[0];
                float4 p1 = ((const float4*)ap)[1];
                va[0] = p0.x; va[1] = p0.y; va[2] = p0.z; va[3] = p0.w;
                va[4] = p1.x; va[5] = p1.y; va[6] = p1.z; va[7] = p1.w;
                if constexpr (BN_RELU_IN) {
                    int kk0 = kc * 32 + af;
                    float4 sc0 = *(const float4*)(scale + kk0);
                    float4 sc1 = *(const float4*)(scale + kk0 + 4);
                    float4 sh0 = *(const float4*)(shift + kk0);
                    float4 sh1 = *(const float4*)(shift + kk0 + 4);
                    va[0] = fmaxf(va[0] * sc0.x + sh0.x, 0.f);
                    va[1] = fmaxf(va[1] * sc0.y + sh0.y, 0.f);
                    va[2] = fmaxf(va[2] * sc0.z + sh0.z, 0.f);
                    va[3] = fmaxf(va[3] * sc0.w + sh0.w, 0.f);
                    va[4] = fmaxf(va[4] * sc1.x + sh1.x, 0.f);
                    va[5] = fmaxf(va[5] * sc1.y + sh1.y, 0.f);
                    va[6] = fmaxf(va[6] * sc1.z + sh1.z, 0.f);
                    va[7] = fmaxf(va[7] * sc1.w + sh1.w, 0.f);
                }
            } else {
#pragma unroll
                for (int j = 0; j < 8; j++) va[j] = 0.f;
            }
            float4* ad = (float4*)(&s_a[arow][af]);
            float4 q0 = {va[0], va[1], va[2], va[3]};
            float4 q1 = {va[4], va[5], va[6], va[7]};
            ad[0] = q0;
            ad[1] = q1;
        }
        __syncthreads();
#pragma unroll
        for (int k = 0; k < 32; ++k) {
            float4 w = *(const float4*)(&s_w[k][tx * 4]);
            float a[8];
#pragma unroll
            for (int i = 0; i < 8; i++) a[i] = s_a[ty * 8 + i][k];
#pragma unroll
            for (int i = 0; i < 8; i++) {
                acc[i][0] += a[i] * w.x;
                acc[i][1] += a[i] * w.y;
                acc[i][2] += a[i] * w.z;
                acc[i][3] += a[i] * w.w;
            }
        }
    }

    float4 bv = *(const float4*)(bias + tx * 4);
#pragma unroll
    for (int i = 0; i < 8; i++) {
        int r = row0 + ty * 8 + i;
        if (r < N) {
            float4 c;
            c.x = acc[i][0] + bv.x;
            c.y = acc[i][1] + bv.y;
            c.z = acc[i][2] + bv.z;
            c.w = acc[i][3] + bv.w;
            if constexpr (RELU_OUT) {
                c.x = fmaxf(c.x, 0.f);
                c.y = fmaxf(c.y, 0.f);
                c.z = fmaxf(c.z, 0.f);
                c.w = fmaxf(c.w, 0.f);
            }
            *(float4*)(C + (size_t)r * NFEAT + tx * 4) = c;
        }
    }
}

// ---------------- BN column stats ----------------
__global__ void k_colstats(const float* __restrict__ Y, float* __restrict__ stats, int N) {
    int c = threadIdx.x;  // 128 threads
    int r0 = blockIdx.x * 256;
    int r1 = min(r0 + 256, N);
    float s = 0.f, s2 = 0.f;
    for (int r = r0; r < r1; ++r) {
        float v = Y[(size_t)r * NFEAT + c];
        s += v;
        s2 += v * v;
    }
    atomicAdd(&stats[c], s);
    atomicAdd(&stats[NFEAT + c], s2);
}

__global__ void k_bnfinalize(const float* __restrict__ stats, const float* __restrict__ gamma,
                             const float* __restrict__ beta, float* __restrict__ scale,
                             float* __restrict__ shift, int N) {
    int c = threadIdx.x;
    if (c < NFEAT) {
        float mean = stats[c] / (float)N;
        float var = stats[NFEAT + c] / (float)N - mean * mean;
        float inv = rsqrtf(var + BN_EPS);
        float sc = gamma[c] * inv;
        scale[c] = sc;
        shift[c] = beta[c] - mean * sc;
    }
}

// ---------------- pooling + classifier ----------------
__global__ void k_pool(const float* __restrict__ H2, const int* __restrict__ batch,
                       float* __restrict__ pooled, int N) {
    int idx = blockIdx.x * blockDim.x + threadIdx.x;
    int n = idx >> 5;
    int c4 = idx & 31;
    if (n >= N) return;
    int g = batch[n];
    float4 v = ((const float4*)(H2 + (size_t)n * NFEAT))[c4];
    float* p = pooled + (size_t)g * NFEAT + c4 * 4;
    atomicAdd(p + 0, v.x);
    atomicAdd(p + 1, v.y);
    atomicAdd(p + 2, v.z);
    atomicAdd(p + 3, v.w);
}

__global__ void k_final(const float* __restrict__ pooled, const float* __restrict__ Wl,
                        const float* __restrict__ bl, float* __restrict__ out) {
    int idx = blockIdx.x * blockDim.x + threadIdx.x;
    if (idx >= NGRAPHS * TGRAPH) return;
    int g = idx / TGRAPH, t = idx % TGRAPH;
    const float* p = pooled + (size_t)g * NFEAT;
    float acc = bl[t];
    for (int k = 0; k < NFEAT; ++k) acc += p[k] * Wl[k * TGRAPH + t];
    out[idx] = acc;
}

extern "C" void kernel_launch(void* const* d_in, const int* in_sizes, int n_in,
                              void* d_out, int out_size, void* d_ws, size_t ws_size,
                              hipStream_t stream) {
    const float* x = (const float*)d_in[0];
    const int* ei = (const int*)d_in[1];
    const int* batch = (const int*)d_in[2];
    const float* W1a = (const float*)d_in[3];
    const float* b1a = (const float*)d_in[4];
    const float* g1 = (const float*)d_in[5];
    const float* bt1 = (const float*)d_in[6];
    const float* W1b = (const float*)d_in[7];
    const float* b1b = (const float*)d_in[8];
    const float* W2a = (const float*)d_in[9];
    const float* b2a = (const float*)d_in[10];
    const float* g2 = (const float*)d_in[11];
    const float* bt2 = (const float*)d_in[12];
    const float* W2b = (const float*)d_in[13];
    const float* b2b = (const float*)d_in[14];
    const float* Wl = (const float*)d_in[15];
    const float* bl = (const float*)d_in[16];
    float* out = (float*)d_out;

    int N = in_sizes[2];
    int E = in_sizes[1] / 2;
    const int* src = ei;
    const int* dst = ei + E;

    char* ws = (char*)d_ws;
    size_t off = 0;
    auto alloc = [&](size_t bytes) -> void* {
        void* p = ws + off;
        off = (off + bytes + 255) & ~(size_t)255;
        return p;
    };
    float* xa = (float*)alloc((size_t)N * NFEAT * 4);
    float* y = (float*)alloc((size_t)N * NFEAT * 4);
    float* h = (float*)alloc((size_t)N * NFEAT * 4);
    int* adj = (int*)alloc((size_t)E * 4);
    int* rowptr = (int*)alloc((size_t)(N + 1) * 4);
    int* cursor = (int*)alloc((size_t)N * 4);
    int* bsums = (int*)alloc(256 * 4);
    float* stats = (float*)alloc(256 * 4);
    float* scale = (float*)alloc(128 * 4);
    float* shift = (float*)alloc(128 * 4);
    float* pooled = (float*)alloc((size_t)NGRAPHS * NFEAT * 4);

    // ---- CSR build (in-degree; aggregate gathers x[src] per dst) ----
    hipMemsetAsync(cursor, 0, (size_t)N * 4, stream);
    k_degree<<<(E + 255) / 256, 256, 0, stream>>>(dst, cursor, E);
    int B = (N + 1023) / 1024;
    k_scan_partial<<<B, 256, 0, stream>>>(cursor, rowptr, bsums, N);
    k_scan_bsums<<<1, 256, 0, stream>>>(bsums, B);
    k_add_offsets<<<(N + 255) / 256, 256, 0, stream>>>(rowptr, bsums, N, E);
    hipMemcpyAsync(cursor, rowptr, (size_t)N * 4, hipMemcpyDeviceToDevice, stream);
    k_fill<<<(E + 255) / 256, 256, 0, stream>>>(src, dst, cursor, adj, E);

    int aggBlocks = (N * 64 + 255) / 256;
    int gemmBlocks = (N + 63) / 64;

    // ---- layer 1 ----
    k_aggregate<<<aggBlocks, 256, 0, stream>>>(x, rowptr, adj, xa, N);
    k_gemm128<false, false><<<gemmBlocks, 256, 0, stream>>>(xa, W1a, b1a, nullptr, nullptr, y, N);
    hipMemsetAsync(stats, 0, 256 * 4, stream);
    k_colstats<<<(N + 255) / 256, 128, 0, stream>>>(y, stats, N);
    k_bnfinalize<<<1, 128, 0, stream>>>(stats, g1, bt1, scale, shift, N);
    k_gemm128<true, true><<<gemmBlocks, 256, 0, stream>>>(y, W1b, b1b, scale, shift, h, N);

    // ---- layer 2 ----
    k_aggregate<<<aggBlocks, 256, 0, stream>>>(h, rowptr, adj, xa, N);
    k_gemm128<false, false><<<gemmBlocks, 256, 0, stream>>>(xa, W2a, b2a, nullptr, nullptr, y, N);
    hipMemsetAsync(stats, 0, 256 * 4, stream);
    k_colstats<<<(N + 255) / 256, 128, 0, stream>>>(y, stats, N);
    k_bnfinalize<<<1, 128, 0, stream>>>(stats, g2, bt2, scale, shift, N);
    k_gemm128<true, true><<<gemmBlocks, 256, 0, stream>>>(y, W2b, b2b, scale, shift, h, N);

    // ---- pooling + classifier ----
    hipMemsetAsync(pooled, 0, (size_t)NGRAPHS * NFEAT * 4, stream);
    k_pool<<<(N * 32 + 255) / 256, 256, 0, stream>>>(h, batch, pooled, N);
    k_final<<<(NGRAPHS * TGRAPH + 255) / 256, 256, 0, stream>>>(pooled, Wl, bl, out);
}

// Round 2
// 1055.910 us; speedup vs baseline: 1.1544x; 1.1544x over previous
//
#include <hip/hip_runtime.h>
#include <cstdint>
#include <cstddef>

#define NFEAT 128
#define TGRAPH 10
#define NGRAPHS 512
#define BN_EPS 1e-5f

// ---------------- CSR build ----------------
__global__ void k_degree(const int* __restrict__ dst, int* __restrict__ deg, int E) {
    int e = blockIdx.x * blockDim.x + threadIdx.x;
    if (e < E) atomicAdd(&deg[dst[e]], 1);
}

// chunk = 1024 elements per block (256 threads x 4)
__global__ void k_scan_partial(const int* __restrict__ deg, int* __restrict__ out,
                               int* __restrict__ bsums, int N) {
    __shared__ int s[256];
    int t = threadIdx.x;
    int base = blockIdx.x * 1024 + t * 4;
    int v0 = 0, v1 = 0, v2 = 0, v3 = 0;
    if (base + 0 < N) v0 = deg[base + 0];
    if (base + 1 < N) v1 = deg[base + 1];
    if (base + 2 < N) v2 = deg[base + 2];
    if (base + 3 < N) v3 = deg[base + 3];
    int sum = v0 + v1 + v2 + v3;
    s[t] = sum;
    __syncthreads();
    for (int off = 1; off < 256; off <<= 1) {
        int x = 0;
        if (t >= off) x = s[t - off];
        __syncthreads();
        if (t >= off) s[t] += x;
        __syncthreads();
    }
    int run = s[t] - sum;  // exclusive prefix of this thread within block
    if (base + 0 < N) out[base + 0] = run; run += v0;
    if (base + 1 < N) out[base + 1] = run; run += v1;
    if (base + 2 < N) out[base + 2] = run; run += v2;
    if (base + 3 < N) out[base + 3] = run;
    if (t == 255) bsums[blockIdx.x] = s[255];
}

__global__ void k_scan_bsums(int* bsums, int B) {
    __shared__ int s[256];
    int t = threadIdx.x;
    int v = (t < B) ? bsums[t] : 0;
    s[t] = v;
    __syncthreads();
    for (int off = 1; off < 256; off <<= 1) {
        int x = 0;
        if (t >= off) x = s[t - off];
        __syncthreads();
        if (t >= off) s[t] += x;
        __syncthreads();
    }
    if (t < B) bsums[t] = s[t] - v;  // exclusive
}

__global__ void k_add_offsets(int* __restrict__ rowptr, const int* __restrict__ bsums,
                              int N, int E) {
    int i = blockIdx.x * blockDim.x + threadIdx.x;
    if (i < N) rowptr[i] += bsums[i >> 10];
    if (i == 0) rowptr[N] = E;
}

__global__ void k_fill(const int* __restrict__ src, const int* __restrict__ dst,
                       int* __restrict__ cursor, int* __restrict__ adj, int E) {
    int e = blockIdx.x * blockDim.x + threadIdx.x;
    if (e < E) {
        int p = atomicAdd(&cursor[dst[e]], 1);
        adj[p] = src[e];
    }
}

// ---------------- aggregation: xa[n] = x[n] + sum_{s in nbr(n)} x[s] ----------------
// one wave (64 lanes) per node; lane holds cols 2*lane, 2*lane+1
__global__ __launch_bounds__(256) void k_aggregate(const float* __restrict__ X,
                                                   const int* __restrict__ rowptr,
                                                   const int* __restrict__ adj,
                                                   float* __restrict__ XA, int N) {
    int wid = (blockIdx.x * blockDim.x + threadIdx.x) >> 6;
    int lane = threadIdx.x & 63;
    if (wid >= N) return;
    const float2* xr = (const float2*)(X + (size_t)wid * NFEAT);
    float2 acc = xr[lane];  // GIN eps=0: (x + agg)
    int r0 = rowptr[wid], r1 = rowptr[wid + 1];
    for (int e = r0; e < r1; ++e) {
        int s = adj[e];
        float2 v = ((const float2*)(X + (size_t)s * NFEAT))[lane];
        acc.x += v.x;
        acc.y += v.y;
    }
    ((float2*)(XA + (size_t)wid * NFEAT))[lane] = acc;
}

// ---------------- GEMM: C[N,128] = op(A) @ W[128,128] + bias ----------------
// op(A) = BN_RELU_IN ? relu(A*scale[k]+shift[k]) : A ; output relu optional.
// 64 rows per block, 256 threads, thread computes 8 rows x 4 cols.
template <bool BN_RELU_IN, bool RELU_OUT>
__global__ __launch_bounds__(256) void k_gemm128(const float* __restrict__ A,
                                                 const float* __restrict__ W,
                                                 const float* __restrict__ bias,
                                                 const float* __restrict__ scale,
                                                 const float* __restrict__ shift,
                                                 float* __restrict__ C, int N) {
    __shared__ float s_w[32][NFEAT];   // 16 KB: W k-chunk
    __shared__ float s_a[64][36];      // 9 KB: A chunk, row-major, pad 4

    int tid = threadIdx.x;
    int tx = tid & 31;   // cols tx*4 .. tx*4+3
    int ty = tid >> 5;   // rows ty*8 .. ty*8+7
    int row0 = blockIdx.x * 64;

    float acc[8][4];
#pragma unroll
    for (int i = 0; i < 8; i++)
#pragma unroll
        for (int j = 0; j < 4; j++) acc[i][j] = 0.f;

    int arow = tid >> 2;        // 0..63
    int af = (tid & 3) * 8;     // 0,8,16,24
    int gr = row0 + arow;

    for (int kc = 0; kc < 4; ++kc) {
        __syncthreads();
        // stage W chunk [32][128]
        {
            int k = tid >> 3;
            int j0 = (tid & 7) * 16;
            const float4* wsrc = (const float4*)(W + (size_t)(kc * 32 + k) * NFEAT + j0);
            float4* wdst = (float4*)(&s_w[k][j0]);
            wdst[0] = wsrc[0];
            wdst[1] = wsrc[1];
            wdst[2] = wsrc[2];
            wdst[3] = wsrc[3];
        }
        // stage A chunk [64 rows][32 k], 8 k's per thread
        {
            float va[8];
            if (gr < N) {
                const float* ap = A + (size_t)gr * NFEAT + kc * 32 + af;
                float4 p0 = ((const float4*)ap)[0];
                float4 p1 = ((const float4*)ap)[1];
                va[0] = p0.x; va[1] = p0.y; va[2] = p0.z; va[3] = p0.w;
                va[4] = p1.x; va[5] = p1.y; va[6] = p1.z; va[7] = p1.w;
                if constexpr (BN_RELU_IN) {
                    int kk0 = kc * 32 + af;
                    float4 sc0 = *(const float4*)(scale + kk0);
                    float4 sc1 = *(const float4*)(scale + kk0 + 4);
                    float4 sh0 = *(const float4*)(shift + kk0);
                    float4 sh1 = *(const float4*)(shift + kk0 + 4);
                    va[0] = fmaxf(va[0] * sc0.x + sh0.x, 0.f);
                    va[1] = fmaxf(va[1] * sc0.y + sh0.y, 0.f);
                    va[2] = fmaxf(va[2] * sc0.z + sh0.z, 0.f);
                    va[3] = fmaxf(va[3] * sc0.w + sh0.w, 0.f);
                    va[4] = fmaxf(va[4] * sc1.x + sh1.x, 0.f);
                    va[5] = fmaxf(va[5] * sc1.y + sh1.y, 0.f);
                    va[6] = fmaxf(va[6] * sc1.z + sh1.z, 0.f);
                    va[7] = fmaxf(va[7] * sc1.w + sh1.w, 0.f);
                }
            } else {
#pragma unroll
                for (int j = 0; j < 8; j++) va[j] = 0.f;
            }
            float4* ad = (float4*)(&s_a[arow][af]);
            float4 q0 = {va[0], va[1], va[2], va[3]};
            float4 q1 = {va[4], va[5], va[6], va[7]};
            ad[0] = q0;
            ad[1] = q1;
        }
        __syncthreads();
#pragma unroll
        for (int k = 0; k < 32; ++k) {
            float4 w = *(const float4*)(&s_w[k][tx * 4]);
            float a[8];
#pragma unroll
            for (int i = 0; i < 8; i++) a[i] = s_a[ty * 8 + i][k];
#pragma unroll
            for (int i = 0; i < 8; i++) {
                acc[i][0] += a[i] * w.x;
                acc[i][1] += a[i] * w.y;
                acc[i][2] += a[i] * w.z;
                acc[i][3] += a[i] * w.w;
            }
        }
    }

    float4 bv = *(const float4*)(bias + tx * 4);
#pragma unroll
    for (int i = 0; i < 8; i++) {
        int r = row0 + ty * 8 + i;
        if (r < N) {
            float4 c;
            c.x = acc[i][0] + bv.x;
            c.y = acc[i][1] + bv.y;
            c.z = acc[i][2] + bv.z;
            c.w = acc[i][3] + bv.w;
            if constexpr (RELU_OUT) {
                c.x = fmaxf(c.x, 0.f);
                c.y = fmaxf(c.y, 0.f);
                c.z = fmaxf(c.z, 0.f);
                c.w = fmaxf(c.w, 0.f);
            }
            *(float4*)(C + (size_t)r * NFEAT + tx * 4) = c;
        }
    }
}

// ---------------- BN column stats ----------------
__global__ void k_colstats(const float* __restrict__ Y, float* __restrict__ stats, int N) {
    int c = threadIdx.x;  // 128 threads
    int r0 = blockIdx.x * 256;
    int r1 = min(r0 + 256, N);
    float s = 0.f, s2 = 0.f;
    for (int r = r0; r < r1; ++r) {
        float v = Y[(size_t)r * NFEAT + c];
        s += v;
        s2 += v * v;
    }
    atomicAdd(&stats[c], s);
    atomicAdd(&stats[NFEAT + c], s2);
}

__global__ void k_bnfinalize(const float* __restrict__ stats, const float* __restrict__ gamma,
                             const float* __restrict__ beta, float* __restrict__ scale,
                             float* __restrict__ shift, int N) {
    int c = threadIdx.x;
    if (c < NFEAT) {
        float mean = stats[c] / (float)N;
        float var = stats[NFEAT + c] / (float)N - mean * mean;
        float inv = rsqrtf(var + BN_EPS);
        float sc = gamma[c] * inv;
        scale[c] = sc;
        shift[c] = beta[c] - mean * sc;
    }
}

// ---------------- fused pooling + classifier ----------------
// batch is SORTED: one block per graph, binary-search node range, no atomics.
// 128 threads: thread c privately sums column c over the graph's rows
// (coalesced 512B/row), then 10 threads compute out[g*10+t] from LDS.
__global__ __launch_bounds__(128) void k_pool_final(const float* __restrict__ H2,
                                                    const int* __restrict__ batch,
                                                    const float* __restrict__ Wl,
                                                    const float* __restrict__ bl,
                                                    float* __restrict__ out, int N) {
    __shared__ float s_p[NFEAT];
    int g = blockIdx.x;
    int c = threadIdx.x;

    // lower_bound(g) and lower_bound(g+1) over sorted batch[]
    int lo = 0, hi = N;
    while (lo < hi) { int m = (lo + hi) >> 1; if (batch[m] < g) lo = m + 1; else hi = m; }
    int start = lo;
    hi = N;
    while (lo < hi) { int m = (lo + hi) >> 1; if (batch[m] < g + 1) lo = m + 1; else hi = m; }
    int end = lo;

    float s = 0.f;
    for (int n = start; n < end; ++n) s += H2[(size_t)n * NFEAT + c];
    s_p[c] = s;
    __syncthreads();

    if (c < TGRAPH) {
        float acc = bl[c];
#pragma unroll 16
        for (int k = 0; k < NFEAT; ++k) acc += s_p[k] * Wl[k * TGRAPH + c];
        out[g * TGRAPH + c] = acc;
    }
}

extern "C" void kernel_launch(void* const* d_in, const int* in_sizes, int n_in,
                              void* d_out, int out_size, void* d_ws, size_t ws_size,
                              hipStream_t stream) {
    const float* x = (const float*)d_in[0];
    const int* ei = (const int*)d_in[1];
    const int* batch = (const int*)d_in[2];
    const float* W1a = (const float*)d_in[3];
    const float* b1a = (const float*)d_in[4];
    const float* g1 = (const float*)d_in[5];
    const float* bt1 = (const float*)d_in[6];
    const float* W1b = (const float*)d_in[7];
    const float* b1b = (const float*)d_in[8];
    const float* W2a = (const float*)d_in[9];
    const float* b2a = (const float*)d_in[10];
    const float* g2 = (const float*)d_in[11];
    const float* bt2 = (const float*)d_in[12];
    const float* W2b = (const float*)d_in[13];
    const float* b2b = (const float*)d_in[14];
    const float* Wl = (const float*)d_in[15];
    const float* bl = (const float*)d_in[16];
    float* out = (float*)d_out;

    int N = in_sizes[2];
    int E = in_sizes[1] / 2;
    const int* src = ei;
    const int* dst = ei + E;

    char* ws = (char*)d_ws;
    size_t off = 0;
    auto alloc = [&](size_t bytes) -> void* {
        void* p = ws + off;
        off = (off + bytes + 255) & ~(size_t)255;
        return p;
    };
    float* xa = (float*)alloc((size_t)N * NFEAT * 4);
    float* y = (float*)alloc((size_t)N * NFEAT * 4);
    float* h = (float*)alloc((size_t)N * NFEAT * 4);
    int* adj = (int*)alloc((size_t)E * 4);
    int* rowptr = (int*)alloc((size_t)(N + 1) * 4);
    int* cursor = (int*)alloc((size_t)N * 4);
    int* bsums = (int*)alloc(256 * 4);
    float* stats = (float*)alloc(256 * 4);
    float* scale = (float*)alloc(128 * 4);
    float* shift = (float*)alloc(128 * 4);

    // ---- CSR build (in-degree; aggregate gathers x[src] per dst) ----
    hipMemsetAsync(cursor, 0, (size_t)N * 4, stream);
    k_degree<<<(E + 255) / 256, 256, 0, stream>>>(dst, cursor, E);
    int B = (N + 1023) / 1024;
    k_scan_partial<<<B, 256, 0, stream>>>(cursor, rowptr, bsums, N);
    k_scan_bsums<<<1, 256, 0, stream>>>(bsums, B);
    k_add_offsets<<<(N + 255) / 256, 256, 0, stream>>>(rowptr, bsums, N, E);
    hipMemcpyAsync(cursor, rowptr, (size_t)N * 4, hipMemcpyDeviceToDevice, stream);
    k_fill<<<(E + 255) / 256, 256, 0, stream>>>(src, dst, cursor, adj, E);

    int aggBlocks = (N * 64 + 255) / 256;
    int gemmBlocks = (N + 63) / 64;

    // ---- layer 1 ----
    k_aggregate<<<aggBlocks, 256, 0, stream>>>(x, rowptr, adj, xa, N);
    k_gemm128<false, false><<<gemmBlocks, 256, 0, stream>>>(xa, W1a, b1a, nullptr, nullptr, y, N);
    hipMemsetAsync(stats, 0, 256 * 4, stream);
    k_colstats<<<(N + 255) / 256, 128, 0, stream>>>(y, stats, N);
    k_bnfinalize<<<1, 128, 0, stream>>>(stats, g1, bt1, scale, shift, N);
    k_gemm128<true, true><<<gemmBlocks, 256, 0, stream>>>(y, W1b, b1b, scale, shift, h, N);

    // ---- layer 2 ----
    k_aggregate<<<aggBlocks, 256, 0, stream>>>(h, rowptr, adj, xa, N);
    k_gemm128<false, false><<<gemmBlocks, 256, 0, stream>>>(xa, W2a, b2a, nullptr, nullptr, y, N);
    hipMemsetAsync(stats, 0, 256 * 4, stream);
    k_colstats<<<(N + 255) / 256, 128, 0, stream>>>(y, stats, N);
    k_bnfinalize<<<1, 128, 0, stream>>>(stats, g2, bt2, scale, shift, N);
    k_gemm128<true, true><<<gemmBlocks, 256, 0, stream>>>(y, W2b, b2b, scale, shift, h, N);

    // ---- fused pooling + classifier (batch sorted -> no atomics) ----
    k_pool_final<<<NGRAPHS, 128, 0, stream>>>(h, batch, Wl, bl, out, N);
}

// Round 3
// 762.034 us; speedup vs baseline: 1.5996x; 1.3856x over previous
//
#include <hip/hip_runtime.h>
#include <cstdint>
#include <cstddef>

#define NFEAT 128
#define TGRAPH 10
#define NGRAPHS 512
#define BN_EPS 1e-5f

typedef __attribute__((ext_vector_type(8))) short bf16x8;
typedef __attribute__((ext_vector_type(4))) float f32x4;

__device__ __forceinline__ float bf2f(short s) {
    union { unsigned u; float f; } c;
    c.u = ((unsigned)(unsigned short)s) << 16;
    return c.f;
}
__device__ __forceinline__ short f2bf(float f) {
    union { float f; unsigned u; } c;
    c.f = f;
    unsigned u = c.u;
    return (short)((u + 0x7fffu + ((u >> 16) & 1u)) >> 16);
}

// ---------------- CSR build ----------------
__global__ void k_degree(const int* __restrict__ dst, int* __restrict__ deg, int E) {
    int e = blockIdx.x * blockDim.x + threadIdx.x;
    if (e < E) atomicAdd(&deg[dst[e]], 1);
}

__global__ void k_scan_partial(const int* __restrict__ deg, int* __restrict__ out,
                               int* __restrict__ bsums, int N) {
    __shared__ int s[256];
    int t = threadIdx.x;
    int base = blockIdx.x * 1024 + t * 4;
    int v0 = 0, v1 = 0, v2 = 0, v3 = 0;
    if (base + 0 < N) v0 = deg[base + 0];
    if (base + 1 < N) v1 = deg[base + 1];
    if (base + 2 < N) v2 = deg[base + 2];
    if (base + 3 < N) v3 = deg[base + 3];
    int sum = v0 + v1 + v2 + v3;
    s[t] = sum;
    __syncthreads();
    for (int off = 1; off < 256; off <<= 1) {
        int x = 0;
        if (t >= off) x = s[t - off];
        __syncthreads();
        if (t >= off) s[t] += x;
        __syncthreads();
    }
    int run = s[t] - sum;
    if (base + 0 < N) out[base + 0] = run; run += v0;
    if (base + 1 < N) out[base + 1] = run; run += v1;
    if (base + 2 < N) out[base + 2] = run; run += v2;
    if (base + 3 < N) out[base + 3] = run;
    if (t == 255) bsums[blockIdx.x] = s[255];
}

__global__ void k_scan_bsums(int* bsums, int B) {
    __shared__ int s[256];
    int t = threadIdx.x;
    int v = (t < B) ? bsums[t] : 0;
    s[t] = v;
    __syncthreads();
    for (int off = 1; off < 256; off <<= 1) {
        int x = 0;
        if (t >= off) x = s[t - off];
        __syncthreads();
        if (t >= off) s[t] += x;
        __syncthreads();
    }
    if (t < B) bsums[t] = s[t] - v;
}

__global__ void k_add_offsets(int* __restrict__ rowptr, const int* __restrict__ bsums,
                              int N, int E) {
    int i = blockIdx.x * blockDim.x + threadIdx.x;
    if (i < N) rowptr[i] += bsums[i >> 10];
    if (i == 0) rowptr[N] = E;
}

__global__ void k_fill(const int* __restrict__ src, const int* __restrict__ dst,
                       int* __restrict__ cursor, int* __restrict__ adj, int E) {
    int e = blockIdx.x * blockDim.x + threadIdx.x;
    if (e < E) {
        int p = atomicAdd(&cursor[dst[e]], 1);
        adj[p] = src[e];
    }
}

// ---------------- fp32 -> bf16 convert ----------------
__global__ void k_f32_to_bf16(const float* __restrict__ in, short* __restrict__ out, int n4) {
    int i = blockIdx.x * blockDim.x + threadIdx.x;
    if (i < n4) {
        float4 v = ((const float4*)in)[i];
        ushort4 o;
        o.x = (unsigned short)f2bf(v.x);
        o.y = (unsigned short)f2bf(v.y);
        o.z = (unsigned short)f2bf(v.z);
        o.w = (unsigned short)f2bf(v.w);
        ((ushort4*)out)[i] = o;
    }
}

// ---------------- weight prep: fp32 row-major [k][n] -> bf16 B-frag layout ----------------
// frag layout: Wf[((kc*8+ct)*64 + lane)*8 + j] = W[k = kc*32 + (lane>>4)*8 + j][n = ct*16 + (lane&15)]
__global__ void k_prep_w(const float* __restrict__ W0, const float* __restrict__ W1,
                         const float* __restrict__ W2, const float* __restrict__ W3,
                         short* __restrict__ Wf) {
    int idx = blockIdx.x * blockDim.x + threadIdx.x;
    if (idx >= 4 * 16384) return;
    int w = idx >> 14, r = idx & 16383;
    int j = r & 7, lane = (r >> 3) & 63, ct = (r >> 9) & 7, kc = r >> 12;
    int k = kc * 32 + (lane >> 4) * 8 + j;
    int n = ct * 16 + (lane & 15);
    const float* W = (w == 0) ? W0 : (w == 1) ? W1 : (w == 2) ? W2 : W3;
    Wf[idx] = f2bf(W[k * NFEAT + n]);
}

// ---------------- aggregation (bf16): xa[n] = x[n] + sum_{s in nbr(n)} x[s] ----------------
// one wave per node; lane holds cols 2*lane, 2*lane+1 (one dword of 2 bf16)
__global__ __launch_bounds__(256) void k_aggregate_bf(const short* __restrict__ X,
                                                      const int* __restrict__ rowptr,
                                                      const int* __restrict__ adj,
                                                      short* __restrict__ XA, int N) {
    int wid = (blockIdx.x * blockDim.x + threadIdx.x) >> 6;
    int lane = threadIdx.x & 63;
    if (wid >= N) return;
    unsigned sv = *(const unsigned*)(X + (size_t)wid * NFEAT + lane * 2);
    float ax = bf2f((short)(sv & 0xffff));
    float ay = bf2f((short)(sv >> 16));
    int e = rowptr[wid], r1 = rowptr[wid + 1];
    for (; e + 4 <= r1; e += 4) {
        int s0 = adj[e + 0], s1 = adj[e + 1], s2 = adj[e + 2], s3 = adj[e + 3];
        unsigned v0 = *(const unsigned*)(X + (size_t)s0 * NFEAT + lane * 2);
        unsigned v1 = *(const unsigned*)(X + (size_t)s1 * NFEAT + lane * 2);
        unsigned v2 = *(const unsigned*)(X + (size_t)s2 * NFEAT + lane * 2);
        unsigned v3 = *(const unsigned*)(X + (size_t)s3 * NFEAT + lane * 2);
        ax += bf2f((short)(v0 & 0xffff)) + bf2f((short)(v1 & 0xffff)) +
              bf2f((short)(v2 & 0xffff)) + bf2f((short)(v3 & 0xffff));
        ay += bf2f((short)(v0 >> 16)) + bf2f((short)(v1 >> 16)) +
              bf2f((short)(v2 >> 16)) + bf2f((short)(v3 >> 16));
    }
    for (; e < r1; ++e) {
        int s0 = adj[e];
        unsigned v0 = *(const unsigned*)(X + (size_t)s0 * NFEAT + lane * 2);
        ax += bf2f((short)(v0 & 0xffff));
        ay += bf2f((short)(v0 >> 16));
    }
    unsigned o = (unsigned)(unsigned short)f2bf(ax) | ((unsigned)(unsigned short)f2bf(ay) << 16);
    *(unsigned*)(XA + (size_t)wid * NFEAT + lane * 2) = o;
}

// ---------------- MFMA GEMM: C[N,128] = op(A) @ W + bias, bf16 in/out, fp32 accum --------
// 256 threads = 4 waves; wave handles 32 rows (2 row-tiles of 16); block = 128 rows.
// A frags straight from global (row-major bf16); B frags from pre-swizzled Wf (L2-resident).
template <bool BN_RELU_IN, bool RELU_OUT>
__global__ __launch_bounds__(256) void k_gemm_mfma(const short* __restrict__ A,
                                                   const short* __restrict__ Wf,
                                                   const float* __restrict__ bias,
                                                   const float* __restrict__ scale,
                                                   const float* __restrict__ shift,
                                                   short* __restrict__ C, int N) {
    int tid = threadIdx.x;
    int wave = tid >> 6, lane = tid & 63;
    int quad = lane >> 4, l16 = lane & 15;
    int row_base = blockIdx.x * 128 + wave * 32;

    f32x4 acc[2][8];
#pragma unroll
    for (int i = 0; i < 2; i++)
#pragma unroll
        for (int j = 0; j < 8; j++) acc[i][j] = (f32x4){0.f, 0.f, 0.f, 0.f};

    int r0 = row_base + l16;
    int r1 = r0 + 16;

#pragma unroll
    for (int kc = 0; kc < 4; ++kc) {
        int koff = kc * 32 + quad * 8;
        bf16x8 a0 = {}, a1 = {};
        if (r0 < N) a0 = *(const bf16x8*)(A + (size_t)r0 * NFEAT + koff);
        if (r1 < N) a1 = *(const bf16x8*)(A + (size_t)r1 * NFEAT + koff);
        if constexpr (BN_RELU_IN) {
            float sc[8], sh[8];
            *(float4*)(sc) = *(const float4*)(scale + koff);
            *(float4*)(sc + 4) = *(const float4*)(scale + koff + 4);
            *(float4*)(sh) = *(const float4*)(shift + koff);
            *(float4*)(sh + 4) = *(const float4*)(shift + koff + 4);
#pragma unroll
            for (int j = 0; j < 8; j++) {
                float v = fmaxf(bf2f(a0[j]) * sc[j] + sh[j], 0.f);
                float u = fmaxf(bf2f(a1[j]) * sc[j] + sh[j], 0.f);
                a0[j] = f2bf(v);
                a1[j] = f2bf(u);
            }
        }
        const short* wp = Wf + ((size_t)(kc * 8) * 64 + lane) * 8;
#pragma unroll
        for (int ct = 0; ct < 8; ++ct) {
            bf16x8 b = *(const bf16x8*)(wp + (size_t)ct * 64 * 8);
            acc[0][ct] = __builtin_amdgcn_mfma_f32_16x16x32_bf16(a0, b, acc[0][ct], 0, 0, 0);
            acc[1][ct] = __builtin_amdgcn_mfma_f32_16x16x32_bf16(a1, b, acc[1][ct], 0, 0, 0);
        }
    }

    // C/D layout: col = lane&15, row = quad*4 + reg  [m89-verified]
#pragma unroll
    for (int rt = 0; rt < 2; ++rt) {
#pragma unroll
        for (int ct = 0; ct < 8; ++ct) {
            int col = ct * 16 + l16;
            float bv = bias[col];
#pragma unroll
            for (int reg = 0; reg < 4; ++reg) {
                int row = row_base + rt * 16 + quad * 4 + reg;
                if (row < N) {
                    float v = acc[rt][ct][reg] + bv;
                    if constexpr (RELU_OUT) v = fmaxf(v, 0.f);
                    C[(size_t)row * NFEAT + col] = f2bf(v);
                }
            }
        }
    }
}

// ---------------- BN column stats (bf16 input, fp32 accum) ----------------
__global__ void k_colstats_bf(const short* __restrict__ Y, float* __restrict__ stats, int N) {
    int c = threadIdx.x;  // 128 threads
    int r0 = blockIdx.x * 256;
    int r1 = min(r0 + 256, N);
    float s = 0.f, s2 = 0.f;
    for (int r = r0; r < r1; ++r) {
        float v = bf2f(Y[(size_t)r * NFEAT + c]);
        s += v;
        s2 += v * v;
    }
    atomicAdd(&stats[c], s);
    atomicAdd(&stats[NFEAT + c], s2);
}

__global__ void k_bnfinalize(const float* __restrict__ stats, const float* __restrict__ gamma,
                             const float* __restrict__ beta, float* __restrict__ scale,
                             float* __restrict__ shift, int N) {
    int c = threadIdx.x;
    if (c < NFEAT) {
        float mean = stats[c] / (float)N;
        float var = stats[NFEAT + c] / (float)N - mean * mean;
        float inv = rsqrtf(var + BN_EPS);
        float sc = gamma[c] * inv;
        scale[c] = sc;
        shift[c] = beta[c] - mean * sc;
    }
}

// ---------------- fused pooling + classifier (batch sorted, no atomics) ----------------
__global__ __launch_bounds__(128) void k_pool_final(const short* __restrict__ H2,
                                                    const int* __restrict__ batch,
                                                    const float* __restrict__ Wl,
                                                    const float* __restrict__ bl,
                                                    float* __restrict__ out, int N) {
    __shared__ float s_p[NFEAT];
    int g = blockIdx.x;
    int c = threadIdx.x;

    int lo = 0, hi = N;
    while (lo < hi) { int m = (lo + hi) >> 1; if (batch[m] < g) lo = m + 1; else hi = m; }
    int start = lo;
    hi = N;
    while (lo < hi) { int m = (lo + hi) >> 1; if (batch[m] < g + 1) lo = m + 1; else hi = m; }
    int end = lo;

    float s = 0.f;
    for (int n = start; n < end; ++n) s += bf2f(H2[(size_t)n * NFEAT + c]);
    s_p[c] = s;
    __syncthreads();

    if (c < TGRAPH) {
        float acc = bl[c];
#pragma unroll 16
        for (int k = 0; k < NFEAT; ++k) acc += s_p[k] * Wl[k * TGRAPH + c];
        out[g * TGRAPH + c] = acc;
    }
}

extern "C" void kernel_launch(void* const* d_in, const int* in_sizes, int n_in,
                              void* d_out, int out_size, void* d_ws, size_t ws_size,
                              hipStream_t stream) {
    const float* x = (const float*)d_in[0];
    const int* ei = (const int*)d_in[1];
    const int* batch = (const int*)d_in[2];
    const float* W1a = (const float*)d_in[3];
    const float* b1a = (const float*)d_in[4];
    const float* g1 = (const float*)d_in[5];
    const float* bt1 = (const float*)d_in[6];
    const float* W1b = (const float*)d_in[7];
    const float* b1b = (const float*)d_in[8];
    const float* W2a = (const float*)d_in[9];
    const float* b2a = (const float*)d_in[10];
    const float* g2 = (const float*)d_in[11];
    const float* bt2 = (const float*)d_in[12];
    const float* W2b = (const float*)d_in[13];
    const float* b2b = (const float*)d_in[14];
    const float* Wl = (const float*)d_in[15];
    const float* bl = (const float*)d_in[16];
    float* out = (float*)d_out;

    int N = in_sizes[2];
    int E = in_sizes[1] / 2;
    const int* src = ei;
    const int* dst = ei + E;

    char* ws = (char*)d_ws;
    size_t off = 0;
    auto alloc = [&](size_t bytes) -> void* {
        void* p = ws + off;
        off = (off + bytes + 255) & ~(size_t)255;
        return p;
    };
    short* xbf = (short*)alloc((size_t)N * NFEAT * 2);   // bf16 activations
    short* ag = (short*)alloc((size_t)N * NFEAT * 2);
    short* ybf = (short*)alloc((size_t)N * NFEAT * 2);
    short* hbf = (short*)alloc((size_t)N * NFEAT * 2);
    short* h2bf = (short*)alloc((size_t)N * NFEAT * 2);
    short* Wf = (short*)alloc((size_t)4 * 16384 * 2);    // 4 weights, frag layout
    int* adj = (int*)alloc((size_t)E * 4);
    int* rowptr = (int*)alloc((size_t)(N + 1) * 4);
    int* cursor = (int*)alloc((size_t)N * 4);
    int* bsums = (int*)alloc(256 * 4);
    float* stats = (float*)alloc(256 * 4);
    float* scale = (float*)alloc(128 * 4);
    float* shift = (float*)alloc(128 * 4);

    // ---- CSR build ----
    hipMemsetAsync(cursor, 0, (size_t)N * 4, stream);
    k_degree<<<(E + 255) / 256, 256, 0, stream>>>(dst, cursor, E);
    int B = (N + 1023) / 1024;
    k_scan_partial<<<B, 256, 0, stream>>>(cursor, rowptr, bsums, N);
    k_scan_bsums<<<1, 256, 0, stream>>>(bsums, B);
    k_add_offsets<<<(N + 255) / 256, 256, 0, stream>>>(rowptr, bsums, N, E);
    hipMemcpyAsync(cursor, rowptr, (size_t)N * 4, hipMemcpyDeviceToDevice, stream);
    k_fill<<<(E + 255) / 256, 256, 0, stream>>>(src, dst, cursor, adj, E);

    // ---- dtype prep ----
    int n4 = N * NFEAT / 4;
    k_f32_to_bf16<<<(n4 + 255) / 256, 256, 0, stream>>>(x, xbf, n4);
    k_prep_w<<<(4 * 16384 + 255) / 256, 256, 0, stream>>>(W1a, W1b, W2a, W2b, Wf);

    int aggBlocks = (N * 64 + 255) / 256;
    int gemmBlocks = (N + 127) / 128;

    // ---- layer 1 ----
    k_aggregate_bf<<<aggBlocks, 256, 0, stream>>>(xbf, rowptr, adj, ag, N);
    k_gemm_mfma<false, false><<<gemmBlocks, 256, 0, stream>>>(ag, Wf + 0 * 16384, b1a, nullptr, nullptr, ybf, N);
    hipMemsetAsync(stats, 0, 256 * 4, stream);
    k_colstats_bf<<<(N + 255) / 256, 128, 0, stream>>>(ybf, stats, N);
    k_bnfinalize<<<1, 128, 0, stream>>>(stats, g1, bt1, scale, shift, N);
    k_gemm_mfma<true, true><<<gemmBlocks, 256, 0, stream>>>(ybf, Wf + 1 * 16384, b1b, scale, shift, hbf, N);

    // ---- layer 2 ----
    k_aggregate_bf<<<aggBlocks, 256, 0, stream>>>(hbf, rowptr, adj, ag, N);
    k_gemm_mfma<false, false><<<gemmBlocks, 256, 0, stream>>>(ag, Wf + 2 * 16384, b2a, nullptr, nullptr, ybf, N);
    hipMemsetAsync(stats, 0, 256 * 4, stream);
    k_colstats_bf<<<(N + 255) / 256, 128, 0, stream>>>(ybf, stats, N);
    k_bnfinalize<<<1, 128, 0, stream>>>(stats, g2, bt2, scale, shift, N);
    k_gemm_mfma<true, true><<<gemmBlocks, 256, 0, stream>>>(ybf, Wf + 3 * 16384, b2b, scale, shift, h2bf, N);

    // ---- pooling + classifier ----
    k_pool_final<<<NGRAPHS, 128, 0, stream>>>(h2bf, batch, Wl, bl, out, N);
}

// Round 4
// 702.469 us; speedup vs baseline: 1.7352x; 1.0848x over previous
//
#include <hip/hip_runtime.h>
#include <cstdint>
#include <cstddef>

#define NFEAT 128
#define TGRAPH 10
#define NGRAPHS 512
#define BN_EPS 1e-5f
#define BIN_CHUNK 16384

typedef __attribute__((ext_vector_type(8))) short bf16x8;
typedef __attribute__((ext_vector_type(4))) float f32x4;

__device__ __forceinline__ float bf2f(short s) {
    union { unsigned u; float f; } c;
    c.u = ((unsigned)(unsigned short)s) << 16;
    return c.f;
}
__device__ __forceinline__ short f2bf(float f) {
    union { float f; unsigned u; } c;
    c.f = f;
    unsigned u = c.u;
    return (short)((u + 0x7fffu + ((u >> 16) & 1u)) >> 16);
}

// ---------------- CSR build ----------------
__global__ void k_degree(const int* __restrict__ dst, int* __restrict__ deg, int E) {
    int e = blockIdx.x * blockDim.x + threadIdx.x;
    if (e < E) atomicAdd(&deg[dst[e]], 1);
}

__global__ void k_scan_partial(const int* __restrict__ deg, int* __restrict__ out,
                               int* __restrict__ bsums, int N) {
    __shared__ int s[256];
    int t = threadIdx.x;
    int base = blockIdx.x * 1024 + t * 4;
    int v0 = 0, v1 = 0, v2 = 0, v3 = 0;
    if (base + 0 < N) v0 = deg[base + 0];
    if (base + 1 < N) v1 = deg[base + 1];
    if (base + 2 < N) v2 = deg[base + 2];
    if (base + 3 < N) v3 = deg[base + 3];
    int sum = v0 + v1 + v2 + v3;
    s[t] = sum;
    __syncthreads();
    for (int off = 1; off < 256; off <<= 1) {
        int x = 0;
        if (t >= off) x = s[t - off];
        __syncthreads();
        if (t >= off) s[t] += x;
        __syncthreads();
    }
    int run = s[t] - sum;
    if (base + 0 < N) out[base + 0] = run; run += v0;
    if (base + 1 < N) out[base + 1] = run; run += v1;
    if (base + 2 < N) out[base + 2] = run; run += v2;
    if (base + 3 < N) out[base + 3] = run;
    if (t == 255) bsums[blockIdx.x] = s[255];
}

__global__ void k_scan_bsums(int* bsums, int B) {
    __shared__ int s[256];
    int t = threadIdx.x;
    int v = (t < B) ? bsums[t] : 0;
    s[t] = v;
    __syncthreads();
    for (int off = 1; off < 256; off <<= 1) {
        int x = 0;
        if (t >= off) x = s[t - off];
        __syncthreads();
        if (t >= off) s[t] += x;
        __syncthreads();
    }
    if (t < B) bsums[t] = s[t] - v;
}

__global__ void k_add_offsets(int* __restrict__ rowptr, const int* __restrict__ bsums,
                              int N, int E) {
    int i = blockIdx.x * blockDim.x + threadIdx.x;
    if (i < N) rowptr[i] += bsums[i >> 10];
    if (i == 0) rowptr[N] = E;
}

// bucket b covers dst in [b*512,(b+1)*512); its region in binned/adj starts at rowptr[b*512]
__global__ void k_init_cur256(const int* __restrict__ rowptr, int* __restrict__ cur256, int N) {
    int t = threadIdx.x;
    if (t < 256) {
        int node = t * 512;
        cur256[t] = rowptr[node < N ? node : N];
    }
}

// pass B: bin (src,dst) pairs by dst>>9 with coalesced appends
__global__ __launch_bounds__(256) void k_bin_scatter(const int* __restrict__ src,
                                                     const int* __restrict__ dst,
                                                     int* __restrict__ cur256,
                                                     int2* __restrict__ binned, int E) {
    __shared__ int hist[256];
    __shared__ int base[256];
    int t = threadIdx.x;
    int e0 = blockIdx.x * BIN_CHUNK;
    int e1 = min(e0 + BIN_CHUNK, E);
    hist[t] = 0;
    __syncthreads();
    for (int e = e0 + t; e < e1; e += 256) {
        int b = dst[e] >> 9;
        atomicAdd(&hist[b], 1);
    }
    __syncthreads();
    int c = hist[t];
    if (c > 0) base[t] = atomicAdd(&cur256[t], c);
    __syncthreads();
    hist[t] = 0;
    __syncthreads();
    for (int e = e0 + t; e < e1; e += 256) {
        int d = dst[e];
        int b = d >> 9;
        int loc = atomicAdd(&hist[b], 1);
        binned[base[b] + loc] = make_int2(src[e], d);
    }
}

// pass C: scatter within buckets — each bucket's adj span ~32KB stays hot in L2
__global__ void k_bin_fill(const int2* __restrict__ binned, int* __restrict__ cursor,
                           int* __restrict__ adj, int E) {
    int e = blockIdx.x * blockDim.x + threadIdx.x;
    if (e < E) {
        int2 p = binned[e];
        int pos = atomicAdd(&cursor[p.y], 1);
        adj[pos] = p.x;
    }
}

// ---------------- fp32 -> bf16 convert ----------------
__global__ void k_f32_to_bf16(const float* __restrict__ in, short* __restrict__ out, int n4) {
    int i = blockIdx.x * blockDim.x + threadIdx.x;
    if (i < n4) {
        float4 v = ((const float4*)in)[i];
        ushort4 o;
        o.x = (unsigned short)f2bf(v.x);
        o.y = (unsigned short)f2bf(v.y);
        o.z = (unsigned short)f2bf(v.z);
        o.w = (unsigned short)f2bf(v.w);
        ((ushort4*)out)[i] = o;
    }
}

// ---------------- weight prep: fp32 row-major [k][n] -> bf16 B-frag layout ----------------
__global__ void k_prep_w(const float* __restrict__ W0, const float* __restrict__ W1,
                         const float* __restrict__ W2, const float* __restrict__ W3,
                         short* __restrict__ Wf) {
    int idx = blockIdx.x * blockDim.x + threadIdx.x;
    if (idx >= 4 * 16384) return;
    int w = idx >> 14, r = idx & 16383;
    int j = r & 7, lane = (r >> 3) & 63, ct = (r >> 9) & 7, kc = r >> 12;
    int k = kc * 32 + (lane >> 4) * 8 + j;
    int n = ct * 16 + (lane & 15);
    const float* W = (w == 0) ? W0 : (w == 1) ? W1 : (w == 2) ? W2 : W3;
    Wf[idx] = f2bf(W[k * NFEAT + n]);
}

// ---------------- aggregation (bf16) ----------------
__global__ __launch_bounds__(256) void k_aggregate_bf(const short* __restrict__ X,
                                                      const int* __restrict__ rowptr,
                                                      const int* __restrict__ adj,
                                                      short* __restrict__ XA, int N) {
    int wid = (blockIdx.x * blockDim.x + threadIdx.x) >> 6;
    int lane = threadIdx.x & 63;
    if (wid >= N) return;
    unsigned sv = *(const unsigned*)(X + (size_t)wid * NFEAT + lane * 2);
    float ax = bf2f((short)(sv & 0xffff));
    float ay = bf2f((short)(sv >> 16));
    int e = rowptr[wid], r1 = rowptr[wid + 1];
    for (; e + 4 <= r1; e += 4) {
        int s0 = adj[e + 0], s1 = adj[e + 1], s2 = adj[e + 2], s3 = adj[e + 3];
        unsigned v0 = *(const unsigned*)(X + (size_t)s0 * NFEAT + lane * 2);
        unsigned v1 = *(const unsigned*)(X + (size_t)s1 * NFEAT + lane * 2);
        unsigned v2 = *(const unsigned*)(X + (size_t)s2 * NFEAT + lane * 2);
        unsigned v3 = *(const unsigned*)(X + (size_t)s3 * NFEAT + lane * 2);
        ax += bf2f((short)(v0 & 0xffff)) + bf2f((short)(v1 & 0xffff)) +
              bf2f((short)(v2 & 0xffff)) + bf2f((short)(v3 & 0xffff));
        ay += bf2f((short)(v0 >> 16)) + bf2f((short)(v1 >> 16)) +
              bf2f((short)(v2 >> 16)) + bf2f((short)(v3 >> 16));
    }
    for (; e < r1; ++e) {
        int s0 = adj[e];
        unsigned v0 = *(const unsigned*)(X + (size_t)s0 * NFEAT + lane * 2);
        ax += bf2f((short)(v0 & 0xffff));
        ay += bf2f((short)(v0 >> 16));
    }
    unsigned o = (unsigned)(unsigned short)f2bf(ax) | ((unsigned)(unsigned short)f2bf(ay) << 16);
    *(unsigned*)(XA + (size_t)wid * NFEAT + lane * 2) = o;
}

// ---------------- MFMA GEMM (+optional fused BN col-stats on fp32 pre-round values) -------
template <bool BN_RELU_IN, bool RELU_OUT, bool STATS>
__global__ __launch_bounds__(256) void k_gemm_mfma(const short* __restrict__ A,
                                                   const short* __restrict__ Wf,
                                                   const float* __restrict__ bias,
                                                   const float* __restrict__ scale,
                                                   const float* __restrict__ shift,
                                                   float* __restrict__ stats,
                                                   short* __restrict__ C, int N) {
    __shared__ float s_sum[NFEAT];
    __shared__ float s_sq[NFEAT];
    int tid = threadIdx.x;
    int wave = tid >> 6, lane = tid & 63;
    int quad = lane >> 4, l16 = lane & 15;
    int row_base = blockIdx.x * 128 + wave * 32;

    if constexpr (STATS) {
        if (tid < NFEAT) { s_sum[tid] = 0.f; s_sq[tid] = 0.f; }
        __syncthreads();
    }

    f32x4 acc[2][8];
#pragma unroll
    for (int i = 0; i < 2; i++)
#pragma unroll
        for (int j = 0; j < 8; j++) acc[i][j] = (f32x4){0.f, 0.f, 0.f, 0.f};

    int r0 = row_base + l16;
    int r1 = r0 + 16;

#pragma unroll
    for (int kc = 0; kc < 4; ++kc) {
        int koff = kc * 32 + quad * 8;
        bf16x8 a0 = {}, a1 = {};
        if (r0 < N) a0 = *(const bf16x8*)(A + (size_t)r0 * NFEAT + koff);
        if (r1 < N) a1 = *(const bf16x8*)(A + (size_t)r1 * NFEAT + koff);
        if constexpr (BN_RELU_IN) {
            float sc[8], sh[8];
            *(float4*)(sc) = *(const float4*)(scale + koff);
            *(float4*)(sc + 4) = *(const float4*)(scale + koff + 4);
            *(float4*)(sh) = *(const float4*)(shift + koff);
            *(float4*)(sh + 4) = *(const float4*)(shift + koff + 4);
#pragma unroll
            for (int j = 0; j < 8; j++) {
                float v = fmaxf(bf2f(a0[j]) * sc[j] + sh[j], 0.f);
                float u = fmaxf(bf2f(a1[j]) * sc[j] + sh[j], 0.f);
                a0[j] = f2bf(v);
                a1[j] = f2bf(u);
            }
        }
        const short* wp = Wf + ((size_t)(kc * 8) * 64 + lane) * 8;
#pragma unroll
        for (int ct = 0; ct < 8; ++ct) {
            bf16x8 b = *(const bf16x8*)(wp + (size_t)ct * 64 * 8);
            acc[0][ct] = __builtin_amdgcn_mfma_f32_16x16x32_bf16(a0, b, acc[0][ct], 0, 0, 0);
            acc[1][ct] = __builtin_amdgcn_mfma_f32_16x16x32_bf16(a1, b, acc[1][ct], 0, 0, 0);
        }
    }

    // C/D layout: col = lane&15, row = quad*4 + reg
#pragma unroll
    for (int ct = 0; ct < 8; ++ct) {
        int col = ct * 16 + l16;
        float bv = bias[col];
        float ls = 0.f, ls2 = 0.f;
#pragma unroll
        for (int rt = 0; rt < 2; ++rt) {
#pragma unroll
            for (int reg = 0; reg < 4; ++reg) {
                int row = row_base + rt * 16 + quad * 4 + reg;
                if (row < N) {
                    float v = acc[rt][ct][reg] + bv;
                    if constexpr (RELU_OUT) v = fmaxf(v, 0.f);
                    C[(size_t)row * NFEAT + col] = f2bf(v);
                    if constexpr (STATS) { ls += v; ls2 += v * v; }
                }
            }
        }
        if constexpr (STATS) {
            atomicAdd(&s_sum[col], ls);
            atomicAdd(&s_sq[col], ls2);
        }
    }

    if constexpr (STATS) {
        __syncthreads();
        if (tid < NFEAT) {
            atomicAdd(&stats[tid], s_sum[tid]);
            atomicAdd(&stats[NFEAT + tid], s_sq[tid]);
        }
    }
}

__global__ void k_bnfinalize(const float* __restrict__ stats, const float* __restrict__ gamma,
                             const float* __restrict__ beta, float* __restrict__ scale,
                             float* __restrict__ shift, int N) {
    int c = threadIdx.x;
    if (c < NFEAT) {
        float mean = stats[c] / (float)N;
        float var = stats[NFEAT + c] / (float)N - mean * mean;
        float inv = rsqrtf(var + BN_EPS);
        float sc = gamma[c] * inv;
        scale[c] = sc;
        shift[c] = beta[c] - mean * sc;
    }
}

// ---------------- fused pooling + classifier (batch sorted, no atomics) ----------------
__global__ __launch_bounds__(128) void k_pool_final(const short* __restrict__ H2,
                                                    const int* __restrict__ batch,
                                                    const float* __restrict__ Wl,
                                                    const float* __restrict__ bl,
                                                    float* __restrict__ out, int N) {
    __shared__ float s_p[NFEAT];
    int g = blockIdx.x;
    int c = threadIdx.x;

    int lo = 0, hi = N;
    while (lo < hi) { int m = (lo + hi) >> 1; if (batch[m] < g) lo = m + 1; else hi = m; }
    int start = lo;
    hi = N;
    while (lo < hi) { int m = (lo + hi) >> 1; if (batch[m] < g + 1) lo = m + 1; else hi = m; }
    int end = lo;

    float s = 0.f;
    for (int n = start; n < end; ++n) s += bf2f(H2[(size_t)n * NFEAT + c]);
    s_p[c] = s;
    __syncthreads();

    if (c < TGRAPH) {
        float acc = bl[c];
#pragma unroll 16
        for (int k = 0; k < NFEAT; ++k) acc += s_p[k] * Wl[k * TGRAPH + c];
        out[g * TGRAPH + c] = acc;
    }
}

extern "C" void kernel_launch(void* const* d_in, const int* in_sizes, int n_in,
                              void* d_out, int out_size, void* d_ws, size_t ws_size,
                              hipStream_t stream) {
    const float* x = (const float*)d_in[0];
    const int* ei = (const int*)d_in[1];
    const int* batch = (const int*)d_in[2];
    const float* W1a = (const float*)d_in[3];
    const float* b1a = (const float*)d_in[4];
    const float* g1 = (const float*)d_in[5];
    const float* bt1 = (const float*)d_in[6];
    const float* W1b = (const float*)d_in[7];
    const float* b1b = (const float*)d_in[8];
    const float* W2a = (const float*)d_in[9];
    const float* b2a = (const float*)d_in[10];
    const float* g2 = (const float*)d_in[11];
    const float* bt2 = (const float*)d_in[12];
    const float* W2b = (const float*)d_in[13];
    const float* b2b = (const float*)d_in[14];
    const float* Wl = (const float*)d_in[15];
    const float* bl = (const float*)d_in[16];
    float* out = (float*)d_out;

    int N = in_sizes[2];
    int E = in_sizes[1] / 2;
    const int* src = ei;
    const int* dst = ei + E;

    char* ws = (char*)d_ws;
    size_t off = 0;
    auto alloc = [&](size_t bytes) -> void* {
        void* p = ws + off;
        off = (off + bytes + 255) & ~(size_t)255;
        return p;
    };
    short* xbf = (short*)alloc((size_t)N * NFEAT * 2);
    short* ag = (short*)alloc((size_t)N * NFEAT * 2);
    short* ybf = (short*)alloc((size_t)N * NFEAT * 2);
    short* hbf = (short*)alloc((size_t)N * NFEAT * 2);
    short* h2bf = (short*)alloc((size_t)N * NFEAT * 2);
    short* Wf = (short*)alloc((size_t)4 * 16384 * 2);
    int* adj = (int*)alloc((size_t)E * 4);
    int2* binned = (int2*)alloc((size_t)E * 8);
    int* rowptr = (int*)alloc((size_t)(N + 1) * 4);
    int* cursor = (int*)alloc((size_t)N * 4);
    int* cur256 = (int*)alloc(256 * 4);
    int* bsums = (int*)alloc(256 * 4);
    float* stats = (float*)alloc(256 * 4);
    float* scale = (float*)alloc(128 * 4);
    float* shift = (float*)alloc(128 * 4);

    // ---- CSR build (binned two-pass scatter for write locality) ----
    hipMemsetAsync(cursor, 0, (size_t)N * 4, stream);
    k_degree<<<(E + 255) / 256, 256, 0, stream>>>(dst, cursor, E);
    int B = (N + 1023) / 1024;
    k_scan_partial<<<B, 256, 0, stream>>>(cursor, rowptr, bsums, N);
    k_scan_bsums<<<1, 256, 0, stream>>>(bsums, B);
    k_add_offsets<<<(N + 255) / 256, 256, 0, stream>>>(rowptr, bsums, N, E);
    hipMemcpyAsync(cursor, rowptr, (size_t)N * 4, hipMemcpyDeviceToDevice, stream);
    k_init_cur256<<<1, 256, 0, stream>>>(rowptr, cur256, N);
    k_bin_scatter<<<(E + BIN_CHUNK - 1) / BIN_CHUNK, 256, 0, stream>>>(src, dst, cur256, binned, E);
    k_bin_fill<<<(E + 255) / 256, 256, 0, stream>>>(binned, cursor, adj, E);

    // ---- dtype prep ----
    int n4 = N * NFEAT / 4;
    k_f32_to_bf16<<<(n4 + 255) / 256, 256, 0, stream>>>(x, xbf, n4);
    k_prep_w<<<(4 * 16384 + 255) / 256, 256, 0, stream>>>(W1a, W1b, W2a, W2b, Wf);

    int aggBlocks = (N * 64 + 255) / 256;
    int gemmBlocks = (N + 127) / 128;

    // ---- layer 1 ----
    hipMemsetAsync(stats, 0, 256 * 4, stream);
    k_aggregate_bf<<<aggBlocks, 256, 0, stream>>>(xbf, rowptr, adj, ag, N);
    k_gemm_mfma<false, false, true><<<gemmBlocks, 256, 0, stream>>>(ag, Wf + 0 * 16384, b1a, nullptr, nullptr, stats, ybf, N);
    k_bnfinalize<<<1, 128, 0, stream>>>(stats, g1, bt1, scale, shift, N);
    k_gemm_mfma<true, true, false><<<gemmBlocks, 256, 0, stream>>>(ybf, Wf + 1 * 16384, b1b, scale, shift, nullptr, hbf, N);

    // ---- layer 2 ----
    hipMemsetAsync(stats, 0, 256 * 4, stream);
    k_aggregate_bf<<<aggBlocks, 256, 0, stream>>>(hbf, rowptr, adj, ag, N);
    k_gemm_mfma<false, false, true><<<gemmBlocks, 256, 0, stream>>>(ag, Wf + 2 * 16384, b2a, nullptr, nullptr, stats, ybf, N);
    k_bnfinalize<<<1, 128, 0, stream>>>(stats, g2, bt2, scale, shift, N);
    k_gemm_mfma<true, true, false><<<gemmBlocks, 256, 0, stream>>>(ybf, Wf + 3 * 16384, b2b, scale, shift, nullptr, h2bf, N);

    // ---- pooling + classifier ----
    k_pool_final<<<NGRAPHS, 128, 0, stream>>>(h2bf, batch, Wl, bl, out, N);
}

// Round 5
// 661.241 us; speedup vs baseline: 1.8434x; 1.0623x over previous
//
#include <hip/hip_runtime.h>
#include <cstdint>
#include <cstddef>

#define NFEAT 128
#define TGRAPH 10
#define NGRAPHS 512
#define BN_EPS 1e-5f
#define BIN_CHUNK 16384

typedef __attribute__((ext_vector_type(8))) short bf16x8;
typedef __attribute__((ext_vector_type(4))) float f32x4;

__device__ __forceinline__ float bf2f(short s) {
    union { unsigned u; float f; } c;
    c.u = ((unsigned)(unsigned short)s) << 16;
    return c.f;
}
__device__ __forceinline__ short f2bf(float f) {
    union { float f; unsigned u; } c;
    c.f = f;
    unsigned u = c.u;
    return (short)((u + 0x7fffu + ((u >> 16) & 1u)) >> 16);
}

// ---------------- CSR build ----------------
__global__ void k_degree(const int* __restrict__ dst, int* __restrict__ deg, int E) {
    int e = blockIdx.x * blockDim.x + threadIdx.x;
    if (e < E) atomicAdd(&deg[dst[e]], 1);
}

__global__ void k_scan_partial(const int* __restrict__ deg, int* __restrict__ out,
                               int* __restrict__ bsums, int N) {
    __shared__ int s[256];
    int t = threadIdx.x;
    int base = blockIdx.x * 1024 + t * 4;
    int v0 = 0, v1 = 0, v2 = 0, v3 = 0;
    if (base + 0 < N) v0 = deg[base + 0];
    if (base + 1 < N) v1 = deg[base + 1];
    if (base + 2 < N) v2 = deg[base + 2];
    if (base + 3 < N) v3 = deg[base + 3];
    int sum = v0 + v1 + v2 + v3;
    s[t] = sum;
    __syncthreads();
    for (int off = 1; off < 256; off <<= 1) {
        int x = 0;
        if (t >= off) x = s[t - off];
        __syncthreads();
        if (t >= off) s[t] += x;
        __syncthreads();
    }
    int run = s[t] - sum;
    if (base + 0 < N) out[base + 0] = run; run += v0;
    if (base + 1 < N) out[base + 1] = run; run += v1;
    if (base + 2 < N) out[base + 2] = run; run += v2;
    if (base + 3 < N) out[base + 3] = run;
    if (t == 255) bsums[blockIdx.x] = s[255];
}

__global__ void k_scan_bsums(int* bsums, int B) {
    __shared__ int s[256];
    int t = threadIdx.x;
    int v = (t < B) ? bsums[t] : 0;
    s[t] = v;
    __syncthreads();
    for (int off = 1; off < 256; off <<= 1) {
        int x = 0;
        if (t >= off) x = s[t - off];
        __syncthreads();
        if (t >= off) s[t] += x;
        __syncthreads();
    }
    if (t < B) bsums[t] = s[t] - v;
}

__global__ void k_add_offsets(int* __restrict__ rowptr, const int* __restrict__ bsums,
                              int N, int E) {
    int i = blockIdx.x * blockDim.x + threadIdx.x;
    if (i < N) rowptr[i] += bsums[i >> 10];
    if (i == 0) rowptr[N] = E;
}

__global__ void k_init_cur256(const int* __restrict__ rowptr, int* __restrict__ cur256, int N) {
    int t = threadIdx.x;
    if (t < 256) {
        int node = t * 512;
        cur256[t] = rowptr[node < N ? node : N];
    }
}

// pass B: bin (src,dst) pairs by dst>>9 with coalesced appends
__global__ __launch_bounds__(256) void k_bin_scatter(const int* __restrict__ src,
                                                     const int* __restrict__ dst,
                                                     int* __restrict__ cur256,
                                                     int2* __restrict__ binned, int E) {
    __shared__ int hist[256];
    __shared__ int base[256];
    int t = threadIdx.x;
    int e0 = blockIdx.x * BIN_CHUNK;
    int e1 = min(e0 + BIN_CHUNK, E);
    hist[t] = 0;
    __syncthreads();
    for (int e = e0 + t; e < e1; e += 256) {
        int b = dst[e] >> 9;
        atomicAdd(&hist[b], 1);
    }
    __syncthreads();
    int c = hist[t];
    if (c > 0) base[t] = atomicAdd(&cur256[t], c);
    __syncthreads();
    hist[t] = 0;
    __syncthreads();
    for (int e = e0 + t; e < e1; e += 256) {
        int d = dst[e];
        int b = d >> 9;
        int loc = atomicAdd(&hist[b], 1);
        binned[base[b] + loc] = make_int2(src[e], d);
    }
}

// pass C: scatter within buckets — each bucket's adj span ~32KB stays hot in L2
__global__ void k_bin_fill(const int2* __restrict__ binned, int* __restrict__ cursor,
                           int* __restrict__ adj, int E) {
    int e = blockIdx.x * blockDim.x + threadIdx.x;
    if (e < E) {
        int2 p = binned[e];
        int pos = atomicAdd(&cursor[p.y], 1);
        adj[pos] = p.x;
    }
}

// ---------------- fp32 -> bf16 convert ----------------
__global__ void k_f32_to_bf16(const float* __restrict__ in, short* __restrict__ out, int n4) {
    int i = blockIdx.x * blockDim.x + threadIdx.x;
    if (i < n4) {
        float4 v = ((const float4*)in)[i];
        ushort4 o;
        o.x = (unsigned short)f2bf(v.x);
        o.y = (unsigned short)f2bf(v.y);
        o.z = (unsigned short)f2bf(v.z);
        o.w = (unsigned short)f2bf(v.w);
        ((ushort4*)out)[i] = o;
    }
}

// ---------------- weight prep: fp32 row-major [k][n] -> bf16 B-frag layout ----------------
__global__ void k_prep_w(const float* __restrict__ W0, const float* __restrict__ W1,
                         const float* __restrict__ W2, const float* __restrict__ W3,
                         short* __restrict__ Wf) {
    int idx = blockIdx.x * blockDim.x + threadIdx.x;
    if (idx >= 4 * 16384) return;
    int w = idx >> 14, r = idx & 16383;
    int j = r & 7, lane = (r >> 3) & 63, ct = (r >> 9) & 7, kc = r >> 12;
    int k = kc * 32 + (lane >> 4) * 8 + j;
    int n = ct * 16 + (lane & 15);
    const float* W = (w == 0) ? W0 : (w == 1) ? W1 : (w == 2) ? W2 : W3;
    Wf[idx] = f2bf(W[k * NFEAT + n]);
}

// ---------------- aggregation (bf16), 8-deep edge unroll for MLP ----------------
__global__ __launch_bounds__(256) void k_aggregate_bf(const short* __restrict__ X,
                                                      const int* __restrict__ rowptr,
                                                      const int* __restrict__ adj,
                                                      short* __restrict__ XA, int N) {
    int wid = (blockIdx.x * blockDim.x + threadIdx.x) >> 6;
    int lane = threadIdx.x & 63;
    if (wid >= N) return;
    unsigned sv = *(const unsigned*)(X + (size_t)wid * NFEAT + lane * 2);
    float ax = bf2f((short)(sv & 0xffff));
    float ay = bf2f((short)(sv >> 16));
    int e = rowptr[wid], r1 = rowptr[wid + 1];
    for (; e + 8 <= r1; e += 8) {
        int s[8];
#pragma unroll
        for (int j = 0; j < 8; j++) s[j] = adj[e + j];
        unsigned v[8];
#pragma unroll
        for (int j = 0; j < 8; j++)
            v[j] = *(const unsigned*)(X + (size_t)s[j] * NFEAT + lane * 2);
#pragma unroll
        for (int j = 0; j < 8; j++) {
            ax += bf2f((short)(v[j] & 0xffff));
            ay += bf2f((short)(v[j] >> 16));
        }
    }
    for (; e < r1; ++e) {
        int s0 = adj[e];
        unsigned v0 = *(const unsigned*)(X + (size_t)s0 * NFEAT + lane * 2);
        ax += bf2f((short)(v0 & 0xffff));
        ay += bf2f((short)(v0 >> 16));
    }
    unsigned o = (unsigned)(unsigned short)f2bf(ax) | ((unsigned)(unsigned short)f2bf(ay) << 16);
    *(unsigned*)(XA + (size_t)wid * NFEAT + lane * 2) = o;
}

// ---------------- MFMA GEMM (+optional fused BN col-stats on fp32 pre-round values) -------
template <bool BN_RELU_IN, bool RELU_OUT, bool STATS>
__global__ __launch_bounds__(256) void k_gemm_mfma(const short* __restrict__ A,
                                                   const short* __restrict__ Wf,
                                                   const float* __restrict__ bias,
                                                   const float* __restrict__ scale,
                                                   const float* __restrict__ shift,
                                                   float* __restrict__ stats,
                                                   short* __restrict__ C, int N) {
    __shared__ float s_sum[NFEAT];
    __shared__ float s_sq[NFEAT];
    int tid = threadIdx.x;
    int wave = tid >> 6, lane = tid & 63;
    int quad = lane >> 4, l16 = lane & 15;
    int row_base = blockIdx.x * 128 + wave * 32;

    if constexpr (STATS) {
        if (tid < NFEAT) { s_sum[tid] = 0.f; s_sq[tid] = 0.f; }
        __syncthreads();
    }

    f32x4 acc[2][8];
#pragma unroll
    for (int i = 0; i < 2; i++)
#pragma unroll
        for (int j = 0; j < 8; j++) acc[i][j] = (f32x4){0.f, 0.f, 0.f, 0.f};

    int r0 = row_base + l16;
    int r1 = r0 + 16;

#pragma unroll
    for (int kc = 0; kc < 4; ++kc) {
        int koff = kc * 32 + quad * 8;
        bf16x8 a0 = {}, a1 = {};
        if (r0 < N) a0 = *(const bf16x8*)(A + (size_t)r0 * NFEAT + koff);
        if (r1 < N) a1 = *(const bf16x8*)(A + (size_t)r1 * NFEAT + koff);
        if constexpr (BN_RELU_IN) {
            float sc[8], sh[8];
            *(float4*)(sc) = *(const float4*)(scale + koff);
            *(float4*)(sc + 4) = *(const float4*)(scale + koff + 4);
            *(float4*)(sh) = *(const float4*)(shift + koff);
            *(float4*)(sh + 4) = *(const float4*)(shift + koff + 4);
#pragma unroll
            for (int j = 0; j < 8; j++) {
                float v = fmaxf(bf2f(a0[j]) * sc[j] + sh[j], 0.f);
                float u = fmaxf(bf2f(a1[j]) * sc[j] + sh[j], 0.f);
                a0[j] = f2bf(v);
                a1[j] = f2bf(u);
            }
        }
        const short* wp = Wf + ((size_t)(kc * 8) * 64 + lane) * 8;
#pragma unroll
        for (int ct = 0; ct < 8; ++ct) {
            bf16x8 b = *(const bf16x8*)(wp + (size_t)ct * 64 * 8);
            acc[0][ct] = __builtin_amdgcn_mfma_f32_16x16x32_bf16(a0, b, acc[0][ct], 0, 0, 0);
            acc[1][ct] = __builtin_amdgcn_mfma_f32_16x16x32_bf16(a1, b, acc[1][ct], 0, 0, 0);
        }
    }

    // C/D layout: col = lane&15, row = quad*4 + reg
#pragma unroll
    for (int ct = 0; ct < 8; ++ct) {
        int col = ct * 16 + l16;
        float bv = bias[col];
        float ls = 0.f, ls2 = 0.f;
#pragma unroll
        for (int rt = 0; rt < 2; ++rt) {
#pragma unroll
            for (int reg = 0; reg < 4; ++reg) {
                int row = row_base + rt * 16 + quad * 4 + reg;
                if (row < N) {
                    float v = acc[rt][ct][reg] + bv;
                    if constexpr (RELU_OUT) v = fmaxf(v, 0.f);
                    C[(size_t)row * NFEAT + col] = f2bf(v);
                    if constexpr (STATS) { ls += v; ls2 += v * v; }
                }
            }
        }
        if constexpr (STATS) {
            atomicAdd(&s_sum[col], ls);
            atomicAdd(&s_sq[col], ls2);
        }
    }

    if constexpr (STATS) {
        __syncthreads();
        if (tid < NFEAT) {
            atomicAdd(&stats[tid], s_sum[tid]);
            atomicAdd(&stats[NFEAT + tid], s_sq[tid]);
        }
    }
}

__global__ void k_bnfinalize(const float* __restrict__ stats, const float* __restrict__ gamma,
                             const float* __restrict__ beta, float* __restrict__ scale,
                             float* __restrict__ shift, int N) {
    int c = threadIdx.x;
    if (c < NFEAT) {
        float mean = stats[c] / (float)N;
        float var = stats[NFEAT + c] / (float)N - mean * mean;
        float inv = rsqrtf(var + BN_EPS);
        float sc = gamma[c] * inv;
        scale[c] = sc;
        shift[c] = beta[c] - mean * sc;
    }
}

// ---------------- node-parallel pooling (batch sorted; per-run register accum) ----------
// block = 128 rows x 256 threads; thread t: dword-col c2 = t&63, row offset t>>6 (stride 4).
// Flush one atomicAdd pair per graph-run per thread (~1.65 runs/block).
__global__ __launch_bounds__(256) void k_pool2(const short* __restrict__ H2,
                                               const int* __restrict__ batch,
                                               float* __restrict__ pooled, int N) {
    int t = threadIdx.x;
    int c2 = t & 63;
    int rofs = t >> 6;
    int n0 = blockIdx.x * 128;
    int cur = -1;
    float ax = 0.f, ay = 0.f;
    for (int i = 0; i < 32; ++i) {
        int n = n0 + rofs + i * 4;
        if (n >= N) break;
        int g = batch[n];
        if (g != cur) {
            if (cur >= 0) {
                atomicAdd(&pooled[cur * NFEAT + c2 * 2], ax);
                atomicAdd(&pooled[cur * NFEAT + c2 * 2 + 1], ay);
            }
            cur = g; ax = 0.f; ay = 0.f;
        }
        unsigned v = *(const unsigned*)(H2 + (size_t)n * NFEAT + c2 * 2);
        ax += bf2f((short)(v & 0xffff));
        ay += bf2f((short)(v >> 16));
    }
    if (cur >= 0) {
        atomicAdd(&pooled[cur * NFEAT + c2 * 2], ax);
        atomicAdd(&pooled[cur * NFEAT + c2 * 2 + 1], ay);
    }
}

__global__ void k_final(const float* __restrict__ pooled, const float* __restrict__ Wl,
                        const float* __restrict__ bl, float* __restrict__ out) {
    int idx = blockIdx.x * blockDim.x + threadIdx.x;
    if (idx >= NGRAPHS * TGRAPH) return;
    int g = idx / TGRAPH, t = idx % TGRAPH;
    const float* p = pooled + (size_t)g * NFEAT;
    float acc = bl[t];
#pragma unroll 16
    for (int k = 0; k < NFEAT; ++k) acc += p[k] * Wl[k * TGRAPH + t];
    out[idx] = acc;
}

extern "C" void kernel_launch(void* const* d_in, const int* in_sizes, int n_in,
                              void* d_out, int out_size, void* d_ws, size_t ws_size,
                              hipStream_t stream) {
    const float* x = (const float*)d_in[0];
    const int* ei = (const int*)d_in[1];
    const int* batch = (const int*)d_in[2];
    const float* W1a = (const float*)d_in[3];
    const float* b1a = (const float*)d_in[4];
    const float* g1 = (const float*)d_in[5];
    const float* bt1 = (const float*)d_in[6];
    const float* W1b = (const float*)d_in[7];
    const float* b1b = (const float*)d_in[8];
    const float* W2a = (const float*)d_in[9];
    const float* b2a = (const float*)d_in[10];
    const float* g2 = (const float*)d_in[11];
    const float* bt2 = (const float*)d_in[12];
    const float* W2b = (const float*)d_in[13];
    const float* b2b = (const float*)d_in[14];
    const float* Wl = (const float*)d_in[15];
    const float* bl = (const float*)d_in[16];
    float* out = (float*)d_out;

    int N = in_sizes[2];
    int E = in_sizes[1] / 2;
    const int* src = ei;
    const int* dst = ei + E;

    char* ws = (char*)d_ws;
    size_t off = 0;
    auto alloc = [&](size_t bytes) -> void* {
        void* p = ws + off;
        off = (off + bytes + 255) & ~(size_t)255;
        return p;
    };
    short* xbf = (short*)alloc((size_t)N * NFEAT * 2);
    short* ag = (short*)alloc((size_t)N * NFEAT * 2);
    short* ybf = (short*)alloc((size_t)N * NFEAT * 2);
    short* hbf = (short*)alloc((size_t)N * NFEAT * 2);
    short* h2bf = (short*)alloc((size_t)N * NFEAT * 2);
    short* Wf = (short*)alloc((size_t)4 * 16384 * 2);
    int* adj = (int*)alloc((size_t)E * 4);
    int2* binned = (int2*)alloc((size_t)E * 8);
    int* rowptr = (int*)alloc((size_t)(N + 1) * 4);
    int* cursor = (int*)alloc((size_t)N * 4);
    int* cur256 = (int*)alloc(256 * 4);
    int* bsums = (int*)alloc(256 * 4);
    float* stats = (float*)alloc(256 * 4);
    float* scale = (float*)alloc(128 * 4);
    float* shift = (float*)alloc(128 * 4);
    float* pooled = (float*)alloc((size_t)NGRAPHS * NFEAT * 4);

    // ---- CSR build (binned two-pass scatter for write locality) ----
    hipMemsetAsync(cursor, 0, (size_t)N * 4, stream);
    k_degree<<<(E + 255) / 256, 256, 0, stream>>>(dst, cursor, E);
    int B = (N + 1023) / 1024;
    k_scan_partial<<<B, 256, 0, stream>>>(cursor, rowptr, bsums, N);
    k_scan_bsums<<<1, 256, 0, stream>>>(bsums, B);
    k_add_offsets<<<(N + 255) / 256, 256, 0, stream>>>(rowptr, bsums, N, E);
    hipMemcpyAsync(cursor, rowptr, (size_t)N * 4, hipMemcpyDeviceToDevice, stream);
    k_init_cur256<<<1, 256, 0, stream>>>(rowptr, cur256, N);
    k_bin_scatter<<<(E + BIN_CHUNK - 1) / BIN_CHUNK, 256, 0, stream>>>(src, dst, cur256, binned, E);
    k_bin_fill<<<(E + 255) / 256, 256, 0, stream>>>(binned, cursor, adj, E);

    // ---- dtype prep ----
    int n4 = N * NFEAT / 4;
    k_f32_to_bf16<<<(n4 + 255) / 256, 256, 0, stream>>>(x, xbf, n4);
    k_prep_w<<<(4 * 16384 + 255) / 256, 256, 0, stream>>>(W1a, W1b, W2a, W2b, Wf);

    int aggBlocks = (N * 64 + 255) / 256;
    int gemmBlocks = (N + 127) / 128;

    // ---- layer 1 ----
    hipMemsetAsync(stats, 0, 256 * 4, stream);
    k_aggregate_bf<<<aggBlocks, 256, 0, stream>>>(xbf, rowptr, adj, ag, N);
    k_gemm_mfma<false, false, true><<<gemmBlocks, 256, 0, stream>>>(ag, Wf + 0 * 16384, b1a, nullptr, nullptr, stats, ybf, N);
    k_bnfinalize<<<1, 128, 0, stream>>>(stats, g1, bt1, scale, shift, N);
    k_gemm_mfma<true, true, false><<<gemmBlocks, 256, 0, stream>>>(ybf, Wf + 1 * 16384, b1b, scale, shift, nullptr, hbf, N);

    // ---- layer 2 ----
    hipMemsetAsync(stats, 0, 256 * 4, stream);
    k_aggregate_bf<<<aggBlocks, 256, 0, stream>>>(hbf, rowptr, adj, ag, N);
    k_gemm_mfma<false, false, true><<<gemmBlocks, 256, 0, stream>>>(ag, Wf + 2 * 16384, b2a, nullptr, nullptr, stats, ybf, N);
    k_bnfinalize<<<1, 128, 0, stream>>>(stats, g2, bt2, scale, shift, N);
    k_gemm_mfma<true, true, false><<<gemmBlocks, 256, 0, stream>>>(ybf, Wf + 3 * 16384, b2b, scale, shift, nullptr, h2bf, N);

    // ---- node-parallel pooling + classifier ----
    hipMemsetAsync(pooled, 0, (size_t)NGRAPHS * NFEAT * 4, stream);
    k_pool2<<<(N + 127) / 128, 256, 0, stream>>>(h2bf, batch, pooled, N);
    k_final<<<(NGRAPHS * TGRAPH + 255) / 256, 256, 0, stream>>>(pooled, Wl, bl, out);
}

// Round 6
// 631.511 us; speedup vs baseline: 1.9302x; 1.0471x over previous
//
#include <hip/hip_runtime.h>
#include <cstdint>
#include <cstddef>

#define NFEAT 128
#define TGRAPH 10
#define NGRAPHS 512
#define BN_EPS 1e-5f
// 2048 edges/block -> ~782 blocks: keeps all 256 CUs busy (16384 gave 98 blocks = 3% occupancy)
#define BIN_CHUNK 2048

typedef __attribute__((ext_vector_type(8))) short bf16x8;
typedef __attribute__((ext_vector_type(4))) float f32x4;

__device__ __forceinline__ float bf2f(short s) {
    union { unsigned u; float f; } c;
    c.u = ((unsigned)(unsigned short)s) << 16;
    return c.f;
}
__device__ __forceinline__ short f2bf(float f) {
    union { float f; unsigned u; } c;
    c.f = f;
    unsigned u = c.u;
    return (short)((u + 0x7fffu + ((u >> 16) & 1u)) >> 16);
}

// ---------------- CSR build ----------------
__global__ void k_degree(const int* __restrict__ dst, int* __restrict__ deg, int E) {
    int e = blockIdx.x * blockDim.x + threadIdx.x;
    if (e < E) atomicAdd(&deg[dst[e]], 1);
}

__global__ void k_scan_partial(const int* __restrict__ deg, int* __restrict__ out,
                               int* __restrict__ bsums, int N) {
    __shared__ int s[256];
    int t = threadIdx.x;
    int base = blockIdx.x * 1024 + t * 4;
    int v0 = 0, v1 = 0, v2 = 0, v3 = 0;
    if (base + 0 < N) v0 = deg[base + 0];
    if (base + 1 < N) v1 = deg[base + 1];
    if (base + 2 < N) v2 = deg[base + 2];
    if (base + 3 < N) v3 = deg[base + 3];
    int sum = v0 + v1 + v2 + v3;
    s[t] = sum;
    __syncthreads();
    for (int off = 1; off < 256; off <<= 1) {
        int x = 0;
        if (t >= off) x = s[t - off];
        __syncthreads();
        if (t >= off) s[t] += x;
        __syncthreads();
    }
    int run = s[t] - sum;
    if (base + 0 < N) out[base + 0] = run; run += v0;
    if (base + 1 < N) out[base + 1] = run; run += v1;
    if (base + 2 < N) out[base + 2] = run; run += v2;
    if (base + 3 < N) out[base + 3] = run;
    if (t == 255) bsums[blockIdx.x] = s[255];
}

__global__ void k_scan_bsums(int* bsums, int B) {
    __shared__ int s[256];
    int t = threadIdx.x;
    int v = (t < B) ? bsums[t] : 0;
    s[t] = v;
    __syncthreads();
    for (int off = 1; off < 256; off <<= 1) {
        int x = 0;
        if (t >= off) x = s[t - off];
        __syncthreads();
        if (t >= off) s[t] += x;
        __syncthreads();
    }
    if (t < B) bsums[t] = s[t] - v;
}

__global__ void k_add_offsets(int* __restrict__ rowptr, const int* __restrict__ bsums,
                              int N, int E) {
    int i = blockIdx.x * blockDim.x + threadIdx.x;
    if (i < N) rowptr[i] += bsums[i >> 10];
    if (i == 0) rowptr[N] = E;
}

__global__ void k_init_cur256(const int* __restrict__ rowptr, int* __restrict__ cur256, int N) {
    int t = threadIdx.x;
    if (t < 256) {
        int node = t * 512;
        cur256[t] = rowptr[node < N ? node : N];
    }
}

// pass B: bin (src,dst) pairs by dst>>9 with coalesced appends
__global__ __launch_bounds__(256) void k_bin_scatter(const int* __restrict__ src,
                                                     const int* __restrict__ dst,
                                                     int* __restrict__ cur256,
                                                     int2* __restrict__ binned, int E) {
    __shared__ int hist[256];
    __shared__ int base[256];
    int t = threadIdx.x;
    int e0 = blockIdx.x * BIN_CHUNK;
    int e1 = min(e0 + BIN_CHUNK, E);
    hist[t] = 0;
    __syncthreads();
    for (int e = e0 + t; e < e1; e += 256) {
        int b = dst[e] >> 9;
        atomicAdd(&hist[b], 1);
    }
    __syncthreads();
    int c = hist[t];
    if (c > 0) base[t] = atomicAdd(&cur256[t], c);
    __syncthreads();
    hist[t] = 0;
    __syncthreads();
    for (int e = e0 + t; e < e1; e += 256) {
        int d = dst[e];
        int b = d >> 9;
        int loc = atomicAdd(&hist[b], 1);
        binned[base[b] + loc] = make_int2(src[e], d);
    }
}

// pass C: scatter within buckets — each bucket's adj span ~32KB stays hot in L2
__global__ void k_bin_fill(const int2* __restrict__ binned, int* __restrict__ cursor,
                           int* __restrict__ adj, int E) {
    int e = blockIdx.x * blockDim.x + threadIdx.x;
    if (e < E) {
        int2 p = binned[e];
        int pos = atomicAdd(&cursor[p.y], 1);
        adj[pos] = p.x;
    }
}

// ---------------- fp32 -> bf16 convert ----------------
__global__ void k_f32_to_bf16(const float* __restrict__ in, short* __restrict__ out, int n4) {
    int i = blockIdx.x * blockDim.x + threadIdx.x;
    if (i < n4) {
        float4 v = ((const float4*)in)[i];
        ushort4 o;
        o.x = (unsigned short)f2bf(v.x);
        o.y = (unsigned short)f2bf(v.y);
        o.z = (unsigned short)f2bf(v.z);
        o.w = (unsigned short)f2bf(v.w);
        ((ushort4*)out)[i] = o;
    }
}

// ---------------- weight prep: fp32 row-major [k][n] -> bf16 B-frag layout ----------------
__global__ void k_prep_w(const float* __restrict__ W0, const float* __restrict__ W1,
                         const float* __restrict__ W2, const float* __restrict__ W3,
                         short* __restrict__ Wf) {
    int idx = blockIdx.x * blockDim.x + threadIdx.x;
    if (idx >= 4 * 16384) return;
    int w = idx >> 14, r = idx & 16383;
    int j = r & 7, lane = (r >> 3) & 63, ct = (r >> 9) & 7, kc = r >> 12;
    int k = kc * 32 + (lane >> 4) * 8 + j;
    int n = ct * 16 + (lane & 15);
    const float* W = (w == 0) ? W0 : (w == 1) ? W1 : (w == 2) ? W2 : W3;
    Wf[idx] = f2bf(W[k * NFEAT + n]);
}

// ---------------- aggregation (bf16), 8-deep edge unroll for MLP ----------------
__global__ __launch_bounds__(256) void k_aggregate_bf(const short* __restrict__ X,
                                                      const int* __restrict__ rowptr,
                                                      const int* __restrict__ adj,
                                                      short* __restrict__ XA, int N) {
    int wid = (blockIdx.x * blockDim.x + threadIdx.x) >> 6;
    int lane = threadIdx.x & 63;
    if (wid >= N) return;
    unsigned sv = *(const unsigned*)(X + (size_t)wid * NFEAT + lane * 2);
    float ax = bf2f((short)(sv & 0xffff));
    float ay = bf2f((short)(sv >> 16));
    int e = rowptr[wid], r1 = rowptr[wid + 1];
    for (; e + 8 <= r1; e += 8) {
        int s[8];
#pragma unroll
        for (int j = 0; j < 8; j++) s[j] = adj[e + j];
        unsigned v[8];
#pragma unroll
        for (int j = 0; j < 8; j++)
            v[j] = *(const unsigned*)(X + (size_t)s[j] * NFEAT + lane * 2);
#pragma unroll
        for (int j = 0; j < 8; j++) {
            ax += bf2f((short)(v[j] & 0xffff));
            ay += bf2f((short)(v[j] >> 16));
        }
    }
    for (; e < r1; ++e) {
        int s0 = adj[e];
        unsigned v0 = *(const unsigned*)(X + (size_t)s0 * NFEAT + lane * 2);
        ax += bf2f((short)(v0 & 0xffff));
        ay += bf2f((short)(v0 >> 16));
    }
    unsigned o = (unsigned)(unsigned short)f2bf(ax) | ((unsigned)(unsigned short)f2bf(ay) << 16);
    *(unsigned*)(XA + (size_t)wid * NFEAT + lane * 2) = o;
}

// ---------------- MFMA GEMM (+optional fused BN col-stats on fp32 pre-round values) -------
template <bool BN_RELU_IN, bool RELU_OUT, bool STATS>
__global__ __launch_bounds__(256) void k_gemm_mfma(const short* __restrict__ A,
                                                   const short* __restrict__ Wf,
                                                   const float* __restrict__ bias,
                                                   const float* __restrict__ scale,
                                                   const float* __restrict__ shift,
                                                   float* __restrict__ stats,
                                                   short* __restrict__ C, int N) {
    __shared__ float s_sum[NFEAT];
    __shared__ float s_sq[NFEAT];
    int tid = threadIdx.x;
    int wave = tid >> 6, lane = tid & 63;
    int quad = lane >> 4, l16 = lane & 15;
    int row_base = blockIdx.x * 128 + wave * 32;

    if constexpr (STATS) {
        if (tid < NFEAT) { s_sum[tid] = 0.f; s_sq[tid] = 0.f; }
        __syncthreads();
    }

    f32x4 acc[2][8];
#pragma unroll
    for (int i = 0; i < 2; i++)
#pragma unroll
        for (int j = 0; j < 8; j++) acc[i][j] = (f32x4){0.f, 0.f, 0.f, 0.f};

    int r0 = row_base + l16;
    int r1 = r0 + 16;

#pragma unroll
    for (int kc = 0; kc < 4; ++kc) {
        int koff = kc * 32 + quad * 8;
        bf16x8 a0 = {}, a1 = {};
        if (r0 < N) a0 = *(const bf16x8*)(A + (size_t)r0 * NFEAT + koff);
        if (r1 < N) a1 = *(const bf16x8*)(A + (size_t)r1 * NFEAT + koff);
        if constexpr (BN_RELU_IN) {
            float sc[8], sh[8];
            *(float4*)(sc) = *(const float4*)(scale + koff);
            *(float4*)(sc + 4) = *(const float4*)(scale + koff + 4);
            *(float4*)(sh) = *(const float4*)(shift + koff);
            *(float4*)(sh + 4) = *(const float4*)(shift + koff + 4);
#pragma unroll
            for (int j = 0; j < 8; j++) {
                float v = fmaxf(bf2f(a0[j]) * sc[j] + sh[j], 0.f);
                float u = fmaxf(bf2f(a1[j]) * sc[j] + sh[j], 0.f);
                a0[j] = f2bf(v);
                a1[j] = f2bf(u);
            }
        }
        const short* wp = Wf + ((size_t)(kc * 8) * 64 + lane) * 8;
#pragma unroll
        for (int ct = 0; ct < 8; ++ct) {
            bf16x8 b = *(const bf16x8*)(wp + (size_t)ct * 64 * 8);
            acc[0][ct] = __builtin_amdgcn_mfma_f32_16x16x32_bf16(a0, b, acc[0][ct], 0, 0, 0);
            acc[1][ct] = __builtin_amdgcn_mfma_f32_16x16x32_bf16(a1, b, acc[1][ct], 0, 0, 0);
        }
    }

    // C/D layout: col = lane&15, row = quad*4 + reg
#pragma unroll
    for (int ct = 0; ct < 8; ++ct) {
        int col = ct * 16 + l16;
        float bv = bias[col];
        float ls = 0.f, ls2 = 0.f;
#pragma unroll
        for (int rt = 0; rt < 2; ++rt) {
#pragma unroll
            for (int reg = 0; reg < 4; ++reg) {
                int row = row_base + rt * 16 + quad * 4 + reg;
                if (row < N) {
                    float v = acc[rt][ct][reg] + bv;
                    if constexpr (RELU_OUT) v = fmaxf(v, 0.f);
                    C[(size_t)row * NFEAT + col] = f2bf(v);
                    if constexpr (STATS) { ls += v; ls2 += v * v; }
                }
            }
        }
        if constexpr (STATS) {
            atomicAdd(&s_sum[col], ls);
            atomicAdd(&s_sq[col], ls2);
        }
    }

    if constexpr (STATS) {
        __syncthreads();
        if (tid < NFEAT) {
            atomicAdd(&stats[tid], s_sum[tid]);
            atomicAdd(&stats[NFEAT + tid], s_sq[tid]);
        }
    }
}

__global__ void k_bnfinalize(const float* __restrict__ stats, const float* __restrict__ gamma,
                             const float* __restrict__ beta, float* __restrict__ scale,
                             float* __restrict__ shift, int N) {
    int c = threadIdx.x;
    if (c < NFEAT) {
        float mean = stats[c] / (float)N;
        float var = stats[NFEAT + c] / (float)N - mean * mean;
        float inv = rsqrtf(var + BN_EPS);
        float sc = gamma[c] * inv;
        scale[c] = sc;
        shift[c] = beta[c] - mean * sc;
    }
}

// ---------------- node-parallel pooling (batch sorted; per-run register accum) ----------
__global__ __launch_bounds__(256) void k_pool2(const short* __restrict__ H2,
                                               const int* __restrict__ batch,
                                               float* __restrict__ pooled, int N) {
    int t = threadIdx.x;
    int c2 = t & 63;
    int rofs = t >> 6;
    int n0 = blockIdx.x * 128;
    int cur = -1;
    float ax = 0.f, ay = 0.f;
    for (int i = 0; i < 32; ++i) {
        int n = n0 + rofs + i * 4;
        if (n >= N) break;
        int g = batch[n];
        if (g != cur) {
            if (cur >= 0) {
                atomicAdd(&pooled[cur * NFEAT + c2 * 2], ax);
                atomicAdd(&pooled[cur * NFEAT + c2 * 2 + 1], ay);
            }
            cur = g; ax = 0.f; ay = 0.f;
        }
        unsigned v = *(const unsigned*)(H2 + (size_t)n * NFEAT + c2 * 2);
        ax += bf2f((short)(v & 0xffff));
        ay += bf2f((short)(v >> 16));
    }
    if (cur >= 0) {
        atomicAdd(&pooled[cur * NFEAT + c2 * 2], ax);
        atomicAdd(&pooled[cur * NFEAT + c2 * 2 + 1], ay);
    }
}

__global__ void k_final(const float* __restrict__ pooled, const float* __restrict__ Wl,
                        const float* __restrict__ bl, float* __restrict__ out) {
    int idx = blockIdx.x * blockDim.x + threadIdx.x;
    if (idx >= NGRAPHS * TGRAPH) return;
    int g = idx / TGRAPH, t = idx % TGRAPH;
    const float* p = pooled + (size_t)g * NFEAT;
    float acc = bl[t];
#pragma unroll 16
    for (int k = 0; k < NFEAT; ++k) acc += p[k] * Wl[k * TGRAPH + t];
    out[idx] = acc;
}

extern "C" void kernel_launch(void* const* d_in, const int* in_sizes, int n_in,
                              void* d_out, int out_size, void* d_ws, size_t ws_size,
                              hipStream_t stream) {
    const float* x = (const float*)d_in[0];
    const int* ei = (const int*)d_in[1];
    const int* batch = (const int*)d_in[2];
    const float* W1a = (const float*)d_in[3];
    const float* b1a = (const float*)d_in[4];
    const float* g1 = (const float*)d_in[5];
    const float* bt1 = (const float*)d_in[6];
    const float* W1b = (const float*)d_in[7];
    const float* b1b = (const float*)d_in[8];
    const float* W2a = (const float*)d_in[9];
    const float* b2a = (const float*)d_in[10];
    const float* g2 = (const float*)d_in[11];
    const float* bt2 = (const float*)d_in[12];
    const float* W2b = (const float*)d_in[13];
    const float* b2b = (const float*)d_in[14];
    const float* Wl = (const float*)d_in[15];
    const float* bl = (const float*)d_in[16];
    float* out = (float*)d_out;

    int N = in_sizes[2];
    int E = in_sizes[1] / 2;
    const int* src = ei;
    const int* dst = ei + E;

    char* ws = (char*)d_ws;
    size_t off = 0;
    auto alloc = [&](size_t bytes) -> void* {
        void* p = ws + off;
        off = (off + bytes + 255) & ~(size_t)255;
        return p;
    };
    short* xbf = (short*)alloc((size_t)N * NFEAT * 2);
    short* ag = (short*)alloc((size_t)N * NFEAT * 2);
    short* ybf = (short*)alloc((size_t)N * NFEAT * 2);
    short* hbf = (short*)alloc((size_t)N * NFEAT * 2);
    short* h2bf = (short*)alloc((size_t)N * NFEAT * 2);
    short* Wf = (short*)alloc((size_t)4 * 16384 * 2);
    int* adj = (int*)alloc((size_t)E * 4);
    int2* binned = (int2*)alloc((size_t)E * 8);
    int* rowptr = (int*)alloc((size_t)(N + 1) * 4);
    int* cursor = (int*)alloc((size_t)N * 4);
    int* cur256 = (int*)alloc(256 * 4);
    int* bsums = (int*)alloc(256 * 4);
    float* stats = (float*)alloc(256 * 4);
    float* scale = (float*)alloc(128 * 4);
    float* shift = (float*)alloc(128 * 4);
    float* pooled = (float*)alloc((size_t)NGRAPHS * NFEAT * 4);

    // ---- CSR build (binned two-pass scatter for write locality) ----
    hipMemsetAsync(cursor, 0, (size_t)N * 4, stream);
    k_degree<<<(E + 255) / 256, 256, 0, stream>>>(dst, cursor, E);
    int B = (N + 1023) / 1024;
    k_scan_partial<<<B, 256, 0, stream>>>(cursor, rowptr, bsums, N);
    k_scan_bsums<<<1, 256, 0, stream>>>(bsums, B);
    k_add_offsets<<<(N + 255) / 256, 256, 0, stream>>>(rowptr, bsums, N, E);
    hipMemcpyAsync(cursor, rowptr, (size_t)N * 4, hipMemcpyDeviceToDevice, stream);
    k_init_cur256<<<1, 256, 0, stream>>>(rowptr, cur256, N);
    k_bin_scatter<<<(E + BIN_CHUNK - 1) / BIN_CHUNK, 256, 0, stream>>>(src, dst, cur256, binned, E);
    k_bin_fill<<<(E + 255) / 256, 256, 0, stream>>>(binned, cursor, adj, E);

    // ---- dtype prep ----
    int n4 = N * NFEAT / 4;
    k_f32_to_bf16<<<(n4 + 255) / 256, 256, 0, stream>>>(x, xbf, n4);
    k_prep_w<<<(4 * 16384 + 255) / 256, 256, 0, stream>>>(W1a, W1b, W2a, W2b, Wf);

    int aggBlocks = (N * 64 + 255) / 256;
    int gemmBlocks = (N + 127) / 128;

    // ---- layer 1 ----
    hipMemsetAsync(stats, 0, 256 * 4, stream);
    k_aggregate_bf<<<aggBlocks, 256, 0, stream>>>(xbf, rowptr, adj, ag, N);
    k_gemm_mfma<false, false, true><<<gemmBlocks, 256, 0, stream>>>(ag, Wf + 0 * 16384, b1a, nullptr, nullptr, stats, ybf, N);
    k_bnfinalize<<<1, 128, 0, stream>>>(stats, g1, bt1, scale, shift, N);
    k_gemm_mfma<true, true, false><<<gemmBlocks, 256, 0, stream>>>(ybf, Wf + 1 * 16384, b1b, scale, shift, nullptr, hbf, N);

    // ---- layer 2 ----
    hipMemsetAsync(stats, 0, 256 * 4, stream);
    k_aggregate_bf<<<aggBlocks, 256, 0, stream>>>(hbf, rowptr, adj, ag, N);
    k_gemm_mfma<false, false, true><<<gemmBlocks, 256, 0, stream>>>(ag, Wf + 2 * 16384, b2a, nullptr, nullptr, stats, ybf, N);
    k_bnfinalize<<<1, 128, 0, stream>>>(stats, g2, bt2, scale, shift, N);
    k_gemm_mfma<true, true, false><<<gemmBlocks, 256, 0, stream>>>(ybf, Wf + 3 * 16384, b2b, scale, shift, nullptr, h2bf, N);

    // ---- node-parallel pooling + classifier ----
    hipMemsetAsync(pooled, 0, (size_t)NGRAPHS * NFEAT * 4, stream);
    k_pool2<<<(N + 127) / 128, 256, 0, stream>>>(h2bf, batch, pooled, N);
    k_final<<<(NGRAPHS * TGRAPH + 255) / 256, 256, 0, stream>>>(pooled, Wl, bl, out);
}

// Round 7
// 537.030 us; speedup vs baseline: 2.2697x; 1.1759x over previous
//
#include <hip/hip_runtime.h>
#include <cstdint>
#include <cstddef>

#define NFEAT 128
#define TGRAPH 10
#define NGRAPHS 512
#define BN_EPS 1e-5f
#define BIN_CHUNK 2048

typedef __attribute__((ext_vector_type(8))) short bf16x8;
typedef __attribute__((ext_vector_type(4))) float f32x4;

__device__ __forceinline__ float bf2f(short s) {
    union { unsigned u; float f; } c;
    c.u = ((unsigned)(unsigned short)s) << 16;
    return c.f;
}
__device__ __forceinline__ short f2bf(float f) {
    union { float f; unsigned u; } c;
    c.f = f;
    unsigned u = c.u;
    return (short)((u + 0x7fffu + ((u >> 16) & 1u)) >> 16);
}

// ---------------- CSR build, bucket-local (bucket = dst>>9, <=256 buckets) ----------------
// pass A: 256-bin bucket histogram, LDS-reduced
__global__ __launch_bounds__(256) void k_bucket_hist(const int* __restrict__ dst,
                                                     int* __restrict__ bhist, int E) {
    __shared__ int h[256];
    int t = threadIdx.x;
    h[t] = 0;
    __syncthreads();
    for (int e = blockIdx.x * blockDim.x + t; e < E; e += gridDim.x * blockDim.x)
        atomicAdd(&h[dst[e] >> 9], 1);
    __syncthreads();
    if (h[t]) atomicAdd(&bhist[t], h[t]);
}

// pass A2: scan bucket totals -> bucket bases (+ cursor copy for bin_scatter)
__global__ void k_bucket_scan(const int* __restrict__ bhist, int* __restrict__ bbase,
                              int* __restrict__ cur256, int E) {
    __shared__ int s[256];
    int t = threadIdx.x;
    int v = bhist[t];
    s[t] = v;
    __syncthreads();
    for (int off = 1; off < 256; off <<= 1) {
        int x = 0;
        if (t >= off) x = s[t - off];
        __syncthreads();
        if (t >= off) s[t] += x;
        __syncthreads();
    }
    int excl = s[t] - v;
    bbase[t] = excl;
    cur256[t] = excl;
    if (t == 255) bbase[256] = E;
}

// pass B: bin (src,dst) pairs by bucket with coalesced appends
__global__ __launch_bounds__(256) void k_bin_scatter(const int* __restrict__ src,
                                                     const int* __restrict__ dst,
                                                     int* __restrict__ cur256,
                                                     int2* __restrict__ binned, int E) {
    __shared__ int hist[256];
    __shared__ int base[256];
    int t = threadIdx.x;
    int e0 = blockIdx.x * BIN_CHUNK;
    int e1 = min(e0 + BIN_CHUNK, E);
    hist[t] = 0;
    __syncthreads();
    for (int e = e0 + t; e < e1; e += 256) {
        int b = dst[e] >> 9;
        atomicAdd(&hist[b], 1);
    }
    __syncthreads();
    int c = hist[t];
    if (c > 0) base[t] = atomicAdd(&cur256[t], c);
    __syncthreads();
    hist[t] = 0;
    __syncthreads();
    for (int e = e0 + t; e < e1; e += 256) {
        int d = dst[e];
        int b = d >> 9;
        int loc = atomicAdd(&hist[b], 1);
        binned[base[b] + loc] = make_int2(src[e], d);
    }
}

// pass C: per-bucket degree histogram + scan + scatter, all in LDS (no global atomics)
__global__ __launch_bounds__(512) void k_bucket_csr(const int2* __restrict__ binned,
                                                    const int* __restrict__ bbase,
                                                    int* __restrict__ rowptr,
                                                    int* __restrict__ adj,
                                                    int N, int E, int nb) {
    __shared__ int deg[512];
    __shared__ int cur[512];
    int b = blockIdx.x;
    int t = threadIdx.x;
    int e0 = bbase[b], e1 = bbase[b + 1];
    deg[t] = 0;
    __syncthreads();
    for (int e = e0 + t; e < e1; e += 512)
        atomicAdd(&deg[binned[e].y & 511], 1);
    __syncthreads();
    int v = deg[t];
    for (int off = 1; off < 512; off <<= 1) {
        int x = 0;
        if (t >= off) x = deg[t - off];
        __syncthreads();
        if (t >= off) deg[t] += x;
        __syncthreads();
    }
    int excl = deg[t] - v;
    cur[t] = excl;
    int node = b * 512 + t;
    if (node < N) rowptr[node] = e0 + excl;
    if (b == nb - 1 && t == 0) rowptr[N] = E;
    __syncthreads();
    for (int e = e0 + t; e < e1; e += 512) {
        int2 p = binned[e];
        int loc = atomicAdd(&cur[p.y & 511], 1);
        adj[e0 + loc] = p.x;
    }
}

// ---------------- fused fp32->bf16 convert (x) + weight frag prep ----------------
// frag layout: Wf[((kc*8+ct)*64 + lane)*8 + j] = W[kc*32+(lane>>4)*8+j][ct*16+(lane&15)]
__global__ void k_prep(const float* __restrict__ x, short* __restrict__ xbf,
                       const float* __restrict__ W0, const float* __restrict__ W1,
                       const float* __restrict__ W2, const float* __restrict__ W3,
                       short* __restrict__ Wf, int n4) {
    int i = blockIdx.x * blockDim.x + threadIdx.x;
    if (i < n4) {
        float4 v = ((const float4*)x)[i];
        ushort4 o;
        o.x = (unsigned short)f2bf(v.x);
        o.y = (unsigned short)f2bf(v.y);
        o.z = (unsigned short)f2bf(v.z);
        o.w = (unsigned short)f2bf(v.w);
        ((ushort4*)xbf)[i] = o;
    } else {
        int idx = i - n4;
        if (idx < 4 * 16384) {
            int w = idx >> 14, r = idx & 16383;
            int j = r & 7, lane = (r >> 3) & 63, ct = (r >> 9) & 7, kc = r >> 12;
            int k = kc * 32 + (lane >> 4) * 8 + j;
            int n = ct * 16 + (lane & 15);
            const float* W = (w == 0) ? W0 : (w == 1) ? W1 : (w == 2) ? W2 : W3;
            Wf[idx] = f2bf(W[k * NFEAT + n]);
        }
    }
}

// ---------------- aggregation (bf16): multi-node grid-stride waves ----------------
__global__ __launch_bounds__(256) void k_aggregate_bf(const short* __restrict__ X,
                                                      const int* __restrict__ rowptr,
                                                      const int* __restrict__ adj,
                                                      short* __restrict__ XA, int N) {
    int lane = threadIdx.x & 63;
    int wid = (blockIdx.x * blockDim.x + threadIdx.x) >> 6;
    int nw = (gridDim.x * blockDim.x) >> 6;
    for (; wid < N; wid += nw) {
        unsigned sv = *(const unsigned*)(X + (size_t)wid * NFEAT + lane * 2);
        float ax = bf2f((short)(sv & 0xffff));
        float ay = bf2f((short)(sv >> 16));
        int e = rowptr[wid], r1 = rowptr[wid + 1];
        for (; e + 8 <= r1; e += 8) {
            int s[8];
#pragma unroll
            for (int j = 0; j < 8; j++) s[j] = adj[e + j];
            unsigned v[8];
#pragma unroll
            for (int j = 0; j < 8; j++)
                v[j] = *(const unsigned*)(X + (size_t)s[j] * NFEAT + lane * 2);
#pragma unroll
            for (int j = 0; j < 8; j++) {
                ax += bf2f((short)(v[j] & 0xffff));
                ay += bf2f((short)(v[j] >> 16));
            }
        }
        for (; e < r1; ++e) {
            int s0 = adj[e];
            unsigned v0 = *(const unsigned*)(X + (size_t)s0 * NFEAT + lane * 2);
            ax += bf2f((short)(v0 & 0xffff));
            ay += bf2f((short)(v0 >> 16));
        }
        unsigned o = (unsigned)(unsigned short)f2bf(ax) | ((unsigned)(unsigned short)f2bf(ay) << 16);
        *(unsigned*)(XA + (size_t)wid * NFEAT + lane * 2) = o;
    }
}

// ---------------- MFMA GEMM (+optional fused BN col-stats) ----------------
template <bool BN_RELU_IN, bool RELU_OUT, bool STATS>
__global__ __launch_bounds__(256) void k_gemm_mfma(const short* __restrict__ A,
                                                   const short* __restrict__ Wf,
                                                   const float* __restrict__ bias,
                                                   const float* __restrict__ scale,
                                                   const float* __restrict__ shift,
                                                   float* __restrict__ stats,
                                                   short* __restrict__ C, int N) {
    __shared__ float s_sum[NFEAT];
    __shared__ float s_sq[NFEAT];
    int tid = threadIdx.x;
    int wave = tid >> 6, lane = tid & 63;
    int quad = lane >> 4, l16 = lane & 15;
    int row_base = blockIdx.x * 128 + wave * 32;

    if constexpr (STATS) {
        if (tid < NFEAT) { s_sum[tid] = 0.f; s_sq[tid] = 0.f; }
        __syncthreads();
    }

    f32x4 acc[2][8];
#pragma unroll
    for (int i = 0; i < 2; i++)
#pragma unroll
        for (int j = 0; j < 8; j++) acc[i][j] = (f32x4){0.f, 0.f, 0.f, 0.f};

    int r0 = row_base + l16;
    int r1 = r0 + 16;

#pragma unroll
    for (int kc = 0; kc < 4; ++kc) {
        int koff = kc * 32 + quad * 8;
        bf16x8 a0 = {}, a1 = {};
        if (r0 < N) a0 = *(const bf16x8*)(A + (size_t)r0 * NFEAT + koff);
        if (r1 < N) a1 = *(const bf16x8*)(A + (size_t)r1 * NFEAT + koff);
        if constexpr (BN_RELU_IN) {
            float sc[8], sh[8];
            *(float4*)(sc) = *(const float4*)(scale + koff);
            *(float4*)(sc + 4) = *(const float4*)(scale + koff + 4);
            *(float4*)(sh) = *(const float4*)(shift + koff);
            *(float4*)(sh + 4) = *(const float4*)(shift + koff + 4);
#pragma unroll
            for (int j = 0; j < 8; j++) {
                float v = fmaxf(bf2f(a0[j]) * sc[j] + sh[j], 0.f);
                float u = fmaxf(bf2f(a1[j]) * sc[j] + sh[j], 0.f);
                a0[j] = f2bf(v);
                a1[j] = f2bf(u);
            }
        }
        const short* wp = Wf + ((size_t)(kc * 8) * 64 + lane) * 8;
#pragma unroll
        for (int ct = 0; ct < 8; ++ct) {
            bf16x8 b = *(const bf16x8*)(wp + (size_t)ct * 64 * 8);
            acc[0][ct] = __builtin_amdgcn_mfma_f32_16x16x32_bf16(a0, b, acc[0][ct], 0, 0, 0);
            acc[1][ct] = __builtin_amdgcn_mfma_f32_16x16x32_bf16(a1, b, acc[1][ct], 0, 0, 0);
        }
    }

    // C/D layout: col = lane&15, row = quad*4 + reg
#pragma unroll
    for (int ct = 0; ct < 8; ++ct) {
        int col = ct * 16 + l16;
        float bv = bias[col];
        float ls = 0.f, ls2 = 0.f;
#pragma unroll
        for (int rt = 0; rt < 2; ++rt) {
#pragma unroll
            for (int reg = 0; reg < 4; ++reg) {
                int row = row_base + rt * 16 + quad * 4 + reg;
                if (row < N) {
                    float v = acc[rt][ct][reg] + bv;
                    if constexpr (RELU_OUT) v = fmaxf(v, 0.f);
                    C[(size_t)row * NFEAT + col] = f2bf(v);
                    if constexpr (STATS) { ls += v; ls2 += v * v; }
                }
            }
        }
        if constexpr (STATS) {
            atomicAdd(&s_sum[col], ls);
            atomicAdd(&s_sq[col], ls2);
        }
    }

    if constexpr (STATS) {
        __syncthreads();
        if (tid < NFEAT) {
            atomicAdd(&stats[tid], s_sum[tid]);
            atomicAdd(&stats[NFEAT + tid], s_sq[tid]);
        }
    }
}

__global__ void k_bnfinalize(const float* __restrict__ stats, const float* __restrict__ gamma,
                             const float* __restrict__ beta, float* __restrict__ scale,
                             float* __restrict__ shift, int N) {
    int c = threadIdx.x;
    if (c < NFEAT) {
        float mean = stats[c] / (float)N;
        float var = stats[NFEAT + c] / (float)N - mean * mean;
        float inv = rsqrtf(var + BN_EPS);
        float sc = gamma[c] * inv;
        scale[c] = sc;
        shift[c] = beta[c] - mean * sc;
    }
}

// ---------------- node-parallel pooling (batch sorted; per-run register accum) ----------
__global__ __launch_bounds__(256) void k_pool2(const short* __restrict__ H2,
                                               const int* __restrict__ batch,
                                               float* __restrict__ pooled, int N) {
    int t = threadIdx.x;
    int c2 = t & 63;
    int rofs = t >> 6;
    int n0 = blockIdx.x * 128;
    int cur = -1;
    float ax = 0.f, ay = 0.f;
    for (int i = 0; i < 32; ++i) {
        int n = n0 + rofs + i * 4;
        if (n >= N) break;
        int g = batch[n];
        if (g != cur) {
            if (cur >= 0) {
                atomicAdd(&pooled[cur * NFEAT + c2 * 2], ax);
                atomicAdd(&pooled[cur * NFEAT + c2 * 2 + 1], ay);
            }
            cur = g; ax = 0.f; ay = 0.f;
        }
        unsigned v = *(const unsigned*)(H2 + (size_t)n * NFEAT + c2 * 2);
        ax += bf2f((short)(v & 0xffff));
        ay += bf2f((short)(v >> 16));
    }
    if (cur >= 0) {
        atomicAdd(&pooled[cur * NFEAT + c2 * 2], ax);
        atomicAdd(&pooled[cur * NFEAT + c2 * 2 + 1], ay);
    }
}

__global__ void k_final(const float* __restrict__ pooled, const float* __restrict__ Wl,
                        const float* __restrict__ bl, float* __restrict__ out) {
    int idx = blockIdx.x * blockDim.x + threadIdx.x;
    if (idx >= NGRAPHS * TGRAPH) return;
    int g = idx / TGRAPH, t = idx % TGRAPH;
    const float* p = pooled + (size_t)g * NFEAT;
    float acc = bl[t];
#pragma unroll 16
    for (int k = 0; k < NFEAT; ++k) acc += p[k] * Wl[k * TGRAPH + t];
    out[idx] = acc;
}

extern "C" void kernel_launch(void* const* d_in, const int* in_sizes, int n_in,
                              void* d_out, int out_size, void* d_ws, size_t ws_size,
                              hipStream_t stream) {
    const float* x = (const float*)d_in[0];
    const int* ei = (const int*)d_in[1];
    const int* batch = (const int*)d_in[2];
    const float* W1a = (const float*)d_in[3];
    const float* b1a = (const float*)d_in[4];
    const float* g1 = (const float*)d_in[5];
    const float* bt1 = (const float*)d_in[6];
    const float* W1b = (const float*)d_in[7];
    const float* b1b = (const float*)d_in[8];
    const float* W2a = (const float*)d_in[9];
    const float* b2a = (const float*)d_in[10];
    const float* g2 = (const float*)d_in[11];
    const float* bt2 = (const float*)d_in[12];
    const float* W2b = (const float*)d_in[13];
    const float* b2b = (const float*)d_in[14];
    const float* Wl = (const float*)d_in[15];
    const float* bl = (const float*)d_in[16];
    float* out = (float*)d_out;

    int N = in_sizes[2];
    int E = in_sizes[1] / 2;
    int nb = (N + 511) >> 9;
    const int* src = ei;
    const int* dst = ei + E;

    char* ws = (char*)d_ws;
    size_t off = 0;
    auto alloc = [&](size_t bytes) -> void* {
        void* p = ws + off;
        off = (off + bytes + 255) & ~(size_t)255;
        return p;
    };
    short* xbf = (short*)alloc((size_t)N * NFEAT * 2);
    short* ag = (short*)alloc((size_t)N * NFEAT * 2);
    short* ybf = (short*)alloc((size_t)N * NFEAT * 2);
    short* hbf = (short*)alloc((size_t)N * NFEAT * 2);
    short* h2bf = (short*)alloc((size_t)N * NFEAT * 2);
    short* Wf = (short*)alloc((size_t)4 * 16384 * 2);
    int* adj = (int*)alloc((size_t)E * 4);
    int2* binned = (int2*)alloc((size_t)E * 8);
    int* rowptr = (int*)alloc((size_t)(N + 1) * 4);
    int* bbase = (int*)alloc(257 * 4);
    int* cur256 = (int*)alloc(256 * 4);
    float* scale = (float*)alloc(128 * 4);
    float* shift = (float*)alloc(128 * 4);
    // zero-region: one memset covers bhist + stats1 + stats2 + pooled
    int* bhist = (int*)alloc(256 * 4);
    float* stats1 = (float*)alloc(256 * 4);
    float* stats2 = (float*)alloc(256 * 4);
    float* pooled = (float*)alloc((size_t)NGRAPHS * NFEAT * 4);
    size_t zbytes = (char*)(pooled + (size_t)NGRAPHS * NFEAT) - (char*)bhist;

    hipMemsetAsync(bhist, 0, zbytes, stream);

    // ---- CSR build (bucket-local, no 100k scan, no global-atomic degree/fill) ----
    k_bucket_hist<<<784, 256, 0, stream>>>(dst, bhist, E);
    k_bucket_scan<<<1, 256, 0, stream>>>(bhist, bbase, cur256, E);
    k_bin_scatter<<<(E + BIN_CHUNK - 1) / BIN_CHUNK, 256, 0, stream>>>(src, dst, cur256, binned, E);
    k_bucket_csr<<<nb, 512, 0, stream>>>(binned, bbase, rowptr, adj, N, E, nb);

    // ---- dtype prep (fused) ----
    int n4 = N * NFEAT / 4;
    int prepTot = n4 + 4 * 16384;
    k_prep<<<(prepTot + 255) / 256, 256, 0, stream>>>(x, xbf, W1a, W1b, W2a, W2b, Wf, n4);

    int gemmBlocks = (N + 127) / 128;

    // ---- layer 1 ----
    k_aggregate_bf<<<2048, 256, 0, stream>>>(xbf, rowptr, adj, ag, N);
    k_gemm_mfma<false, false, true><<<gemmBlocks, 256, 0, stream>>>(ag, Wf + 0 * 16384, b1a, nullptr, nullptr, stats1, ybf, N);
    k_bnfinalize<<<1, 128, 0, stream>>>(stats1, g1, bt1, scale, shift, N);
    k_gemm_mfma<true, true, false><<<gemmBlocks, 256, 0, stream>>>(ybf, Wf + 1 * 16384, b1b, scale, shift, nullptr, hbf, N);

    // ---- layer 2 ----
    k_aggregate_bf<<<2048, 256, 0, stream>>>(hbf, rowptr, adj, ag, N);
    k_gemm_mfma<false, false, true><<<gemmBlocks, 256, 0, stream>>>(ag, Wf + 2 * 16384, b2a, nullptr, nullptr, stats2, ybf, N);
    k_bnfinalize<<<1, 128, 0, stream>>>(stats2, g2, bt2, scale, shift, N);
    k_gemm_mfma<true, true, false><<<gemmBlocks, 256, 0, stream>>>(ybf, Wf + 3 * 16384, b2b, scale, shift, nullptr, h2bf, N);

    // ---- pooling + classifier ----
    k_pool2<<<(N + 127) / 128, 256, 0, stream>>>(h2bf, batch, pooled, N);
    k_final<<<(NGRAPHS * TGRAPH + 255) / 256, 256, 0, stream>>>(pooled, Wl, bl, out);
}